// Round 3
// baseline (610.718 us; speedup 1.0000x reference)
//
#include <hip/hip_runtime.h>
#include <cstdint>
#include <cstddef>

#define BQ    4
#define NTOK  8192
#define CDIM  512
#define MDIM  128
#define NA    4096
#define RSEL  2048
#define NKEEP (NTOK - RSEL)   // 6144
#define RESCUE_CAP 2048
#define GAP_DELTA 1e-3f
#define WIN_TAU   1e-3f

typedef float f32x4 __attribute__((ext_vector_type(4)));
typedef short short8 __attribute__((ext_vector_type(8)));

static __device__ __forceinline__ unsigned short bf16rne(float f) {
  unsigned u = __float_as_uint(f);
  return (unsigned short)((u + 0x7FFFu + ((u >> 16) & 1)) >> 16);
}

// ---------------------------------------------------------------------------
// K1: metric = x @ W^T + b, row-normalize, split even/odd rows into ma/mb
// (fp32) AND emit bf16 hi/mid planes for the MFMA scores kernel.
// ---------------------------------------------------------------------------
__global__ __launch_bounds__(256) void k_metric(const float* __restrict__ X,
                                                const float* __restrict__ W,
                                                const float* __restrict__ bias,
                                                float* __restrict__ ma,
                                                float* __restrict__ mb,
                                                unsigned short* __restrict__ maH,
                                                unsigned short* __restrict__ maM,
                                                unsigned short* __restrict__ mbH,
                                                unsigned short* __restrict__ mbM) {
  __shared__ float ldsA[128 * 128];
  __shared__ float ldsB[128 * 128];
  __shared__ float snorm[128 * 16];
  __shared__ float sinv[128];
  const int t = threadIdx.x;
  const int tok0 = blockIdx.x * 128;
  const int r16 = t & 15, g = t >> 4;

  float acc[8][8];
#pragma unroll
  for (int i = 0; i < 8; ++i)
#pragma unroll
    for (int j = 0; j < 8; ++j) acc[i][j] = 0.f;

  for (int kc = 0; kc < 4; ++kc) {
    __syncthreads();
#pragma unroll
    for (int it = 0; it < 16; ++it) {
      int f = it * 256 + t;
      int row = f >> 5, k4 = f & 31;
      float4 xv = *(const float4*)(X + (size_t)(tok0 + row) * CDIM + kc * 128 + k4 * 4);
      *(float4*)&ldsA[row * 128 + ((k4 ^ (row & 7)) << 2)] = xv;
      float4 wv = *(const float4*)(W + (size_t)row * CDIM + kc * 128 + k4 * 4);
      *(float4*)&ldsB[row * 128 + ((k4 ^ ((row >> 3) & 7)) << 2)] = wv;
    }
    __syncthreads();
#pragma unroll 4
    for (int kq = 0; kq < 32; ++kq) {
      float4 av[8], bv[8];
#pragma unroll
      for (int i = 0; i < 8; ++i) {
        int r = r16 + (i << 4);
        av[i] = *(const float4*)&ldsA[r * 128 + ((kq ^ (r & 7)) << 2)];
      }
#pragma unroll
      for (int j = 0; j < 8; ++j) {
        int c = (g << 3) + j;
        bv[j] = *(const float4*)&ldsB[c * 128 + ((kq ^ ((c >> 3) & 7)) << 2)];
      }
#pragma unroll
      for (int i = 0; i < 8; ++i)
#pragma unroll
        for (int j = 0; j < 8; ++j) {
          acc[i][j] = fmaf(av[i].x, bv[j].x, acc[i][j]);
          acc[i][j] = fmaf(av[i].y, bv[j].y, acc[i][j]);
          acc[i][j] = fmaf(av[i].z, bv[j].z, acc[i][j]);
          acc[i][j] = fmaf(av[i].w, bv[j].w, acc[i][j]);
        }
    }
  }

  float bb[8];
#pragma unroll
  for (int j = 0; j < 8; ++j) bb[j] = bias[(g << 3) + j];
#pragma unroll
  for (int i = 0; i < 8; ++i) {
    float s = 0.f;
#pragma unroll
    for (int j = 0; j < 8; ++j) {
      acc[i][j] += bb[j];
      s = fmaf(acc[i][j], acc[i][j], s);
    }
    snorm[(r16 + (i << 4)) * 16 + g] = s;
  }
  __syncthreads();
  if (t < 128) {
    float s = 0.f;
    for (int q = 0; q < 16; ++q) s += snorm[t * 16 + q];
    sinv[t] = 1.0f / sqrtf(s);
  }
  __syncthreads();
#pragma unroll
  for (int i = 0; i < 8; ++i) {
    int r = r16 + (i << 4);
    int tokg = tok0 + r;
    float inv = sinv[r];
    int bq = tokg >> 13, pos = tokg & (NTOK - 1);
    size_t eidx = ((size_t)bq * NA + (pos >> 1)) * MDIM + (g << 3);
    float vv[8];
#pragma unroll
    for (int j = 0; j < 8; ++j) vv[j] = acc[i][j] * inv;
    float* dst = ((pos & 1) ? mb : ma) + eidx;
    *(float4*)dst = make_float4(vv[0], vv[1], vv[2], vv[3]);
    *(float4*)(dst + 4) = make_float4(vv[4], vv[5], vv[6], vv[7]);
    unsigned hB[8], mB[8];
#pragma unroll
    for (int j = 0; j < 8; ++j) {
      hB[j] = bf16rne(vv[j]);
      mB[j] = bf16rne(vv[j] - __uint_as_float(hB[j] << 16));
    }
    uint4 hw, mw;
    hw.x = hB[0] | (hB[1] << 16); hw.y = hB[2] | (hB[3] << 16);
    hw.z = hB[4] | (hB[5] << 16); hw.w = hB[6] | (hB[7] << 16);
    mw.x = mB[0] | (mB[1] << 16); mw.y = mB[2] | (mB[3] << 16);
    mw.z = mB[4] | (mB[5] << 16); mw.w = mB[6] | (mB[7] << 16);
    *(uint4*)(((pos & 1) ? mbH : maH) + eidx) = hw;
    *(uint4*)(((pos & 1) ? mbM : maM) + eidx) = mw;
  }
}

// ---------------------------------------------------------------------------
// K2: scores via split-bf16 MFMA. score ~= hi*hi + hi*mid + mid*hi.
// Block: 128 a-rows x 1024 c (csplit quarter), 16 c-chunks of 64.
// A (hi+mid, K=128) in registers per wave; B chunks double-buffered in LDS
// via global_load_lds with pre-swizzled source. Tracks per-row top-2 + argmax.
// grid = 4 bq x 32 atiles x 4 csplits = 512 blocks, 256 thr.
// ---------------------------------------------------------------------------
__global__ __launch_bounds__(256, 2) void k_scores_mfma(
    const unsigned short* __restrict__ maH, const unsigned short* __restrict__ maM,
    const unsigned short* __restrict__ mbH, const unsigned short* __restrict__ mbM,
    float* __restrict__ pv1, int* __restrict__ pi1, float* __restrict__ pv2) {
  __shared__ __align__(16) char ldsB[65536];  // [buf2][plane2][64c][128k bf16], XOR-swizzled
  const int t = threadIdx.x;
  const int bid = blockIdx.x;
  const int bq = bid >> 7, rem = bid & 127, at = rem >> 2, cs = rem & 3;
  const int a0 = at * 128;
  const int l = t & 63, w = t >> 6;

  // A fragments (K=128 = 4 chunks of 32), hi+mid planes, 32 rows per wave.
  short8 aH[2][4], aM[2][4];
#pragma unroll
  for (int rf = 0; rf < 2; ++rf)
#pragma unroll
    for (int kc = 0; kc < 4; ++kc) {
      size_t aidx = ((size_t)bq * NA + a0 + w * 32 + rf * 16 + (l & 15)) * MDIM
                    + kc * 32 + ((l >> 4) << 3);
      aH[rf][kc] = *(const short8*)(maH + aidx);
      aM[rf][kc] = *(const short8*)(maM + aidx);
    }

  const unsigned short* bplane = (w >> 1) ? mbM : mbH;

  // stage chunk ch2 into buffer bufn: 2048 slots x 16B, wave w covers 512.
  auto stage = [&](int ch2, int bufn) {
    const int c0s = cs * 1024 + ch2 * 64;
#pragma unroll
    for (int j = 0; j < 8; ++j) {
      int cl = (w & 1) * 32 + j * 4 + (l >> 4);
      int ks16 = (l & 15) << 4;
      const char* src = (const char*)bplane
          + (((size_t)bq * NA + c0s + cl) << 8) + (ks16 ^ ((cl & 7) << 4));
      char* dst = ldsB + bufn * 32768 + (w * 512 + j * 64) * 16;
      __builtin_amdgcn_global_load_lds(
          (const __attribute__((address_space(1))) void*)src,
          (__attribute__((address_space(3))) void*)dst, 16, 0, 0);
    }
  };

  float bv1[8], bv2[8];
  int bi1[8];
#pragma unroll
  for (int s = 0; s < 8; ++s) { bv1[s] = -1e30f; bv2[s] = -1e30f; bi1[s] = 0x7FFFFFFF; }

  stage(0, 0);
  __syncthreads();

  int buf = 0;
  for (int ch = 0; ch < 16; ++ch) {
    if (ch + 1 < 16) stage(ch + 1, buf ^ 1);

    f32x4 acc1[2][4], acc2[2][4];
#pragma unroll
    for (int rf = 0; rf < 2; ++rf)
#pragma unroll
      for (int cf = 0; cf < 4; ++cf) { acc1[rf][cf] = 0.f; acc2[rf][cf] = 0.f; }

    const char* base = ldsB + buf * 32768;
#pragma unroll
    for (int kc = 0; kc < 4; ++kc) {
#pragma unroll
      for (int cf = 0; cf < 4; ++cf) {
        int coff = cf * 16 + (l & 15);
        int kbyte = (kc * 64 + ((l >> 4) << 4)) ^ ((coff & 7) << 4);
        short8 bh = *(const short8*)(base + coff * 256 + kbyte);
        short8 bm = *(const short8*)(base + 16384 + coff * 256 + kbyte);
#pragma unroll
        for (int rf = 0; rf < 2; ++rf) {
          acc1[rf][cf] = __builtin_amdgcn_mfma_f32_16x16x32_bf16(aH[rf][kc], bh, acc1[rf][cf], 0, 0, 0);
          acc2[rf][cf] = __builtin_amdgcn_mfma_f32_16x16x32_bf16(aH[rf][kc], bm, acc2[rf][cf], 0, 0, 0);
          acc2[rf][cf] = __builtin_amdgcn_mfma_f32_16x16x32_bf16(aM[rf][kc], bh, acc2[rf][cf], 0, 0, 0);
        }
      }
    }

    const int cbase = cs * 1024 + ch * 64;
#pragma unroll
    for (int rf = 0; rf < 2; ++rf)
#pragma unroll
      for (int cf = 0; cf < 4; ++cf) {
        int cg = cbase + cf * 16 + (l & 15);
        f32x4 v4 = acc1[rf][cf] + acc2[rf][cf];
#pragma unroll
        for (int r2 = 0; r2 < 4; ++r2) {
          float v = v4[r2];
          int s = rf * 4 + r2;
          if (v > bv1[s]) { bv2[s] = bv1[s]; bv1[s] = v; bi1[s] = cg; }
          else if (v > bv2[s]) bv2[s] = v;
        }
      }
    __syncthreads();
    buf ^= 1;
  }

  // cross-lane top2 reduce over the 16 cols sharing each row, then write.
#pragma unroll
  for (int s = 0; s < 8; ++s) {
    float v1 = bv1[s], v2 = bv2[s];
    int i1 = bi1[s];
#pragma unroll
    for (int m = 1; m < 16; m <<= 1) {
      float V1 = __shfl_xor(v1, m);
      int I1 = __shfl_xor(i1, m);
      float V2 = __shfl_xor(v2, m);
      bool take = (V1 > v1) || (V1 == v1 && I1 < i1);
      float lose = take ? v1 : V1;
      if (take) { v1 = V1; i1 = I1; }
      v2 = fmaxf(fmaxf(v2, V2), lose);
    }
    if ((l & 15) == s) {
      int row = a0 + w * 32 + (s >> 2) * 16 + ((l >> 4) << 2) + (s & 3);
      size_t off = ((size_t)(bq * 4 + cs)) * NA + row;
      pv1[off] = v1; pi1[off] = i1; pv2[off] = v2;
    }
  }
}

// K3: merge the 4 csplit partials -> value, node, gap
__global__ void k_merge4(const float* __restrict__ pv1, const int* __restrict__ pi1,
                         const float* __restrict__ pv2,
                         float* __restrict__ valA, int* __restrict__ nodeA,
                         float* __restrict__ gapA) {
  int i = blockIdx.x * 256 + threadIdx.x;
  if (i >= BQ * NA) return;
  int bq = i >> 12, row = i & (NA - 1);
  float v1 = -1e30f, v2 = -1e30f;
  int i1 = 0x7FFFFFFF;
#pragma unroll
  for (int cspl = 0; cspl < 4; ++cspl) {
    size_t o = ((size_t)(bq * 4 + cspl)) * NA + row;
    float V1 = pv1[o], V2 = pv2[o];
    int I1 = pi1[o];
    bool take = (V1 > v1) || (V1 == v1 && I1 < i1);
    float lose = take ? v1 : V1;
    if (take) { v1 = V1; i1 = I1; }
    v2 = fmaxf(fmaxf(v2, V2), lose);
  }
  valA[i] = v1; nodeA[i] = i1; gapA[i] = v1 - v2;
}

// K4: per-batch: sort approx values, find rank-2048 value vb, mark+compact
// rescue rows (top-2 gap < delta OR |v - vb| <= tau).
__global__ __launch_bounds__(1024) void k_mark(const float* __restrict__ valA,
                                               const float* __restrict__ gapA,
                                               int* __restrict__ rescueCnt,
                                               int* __restrict__ rescueIdx) {
  __shared__ unsigned long long keys[NA];
  __shared__ float vbS;
  const int b = blockIdx.x, t = threadIdx.x;
  for (int p = t; p < NA; p += 1024) {
    float v = valA[(size_t)b * NA + p];
    unsigned u = __float_as_uint(v);
    unsigned mono = u ^ ((u >> 31) ? 0xFFFFFFFFu : 0x80000000u);
    keys[p] = ((unsigned long long)(~mono) << 32) | (unsigned)p;
  }
  __syncthreads();
  for (int k = 2; k <= NA; k <<= 1) {
    for (int j = k >> 1; j > 0; j >>= 1) {
      for (int p = t; p < NA; p += 1024) {
        int q = p ^ j;
        if (q > p) {
          bool up = ((p & k) == 0);
          unsigned long long a = keys[p], c = keys[q];
          if ((a > c) == up) { keys[p] = c; keys[q] = a; }
        }
      }
      __syncthreads();
    }
  }
  if (t == 0) {
    unsigned mono = ~(unsigned)(keys[RSEL - 1] >> 32);
    unsigned u = (mono >> 31) ? (mono ^ 0x80000000u) : ~mono;
    vbS = __uint_as_float(u);
  }
  __syncthreads();
  float vb = vbS;
  for (int p = t; p < NA; p += 1024) {
    size_t o = (size_t)b * NA + p;
    if (gapA[o] < GAP_DELTA || fabsf(valA[o] - vb) <= WIN_TAU) {
      int slot = atomicAdd(&rescueCnt[b], 1);
      if (slot < RESCUE_CAP) rescueIdx[b * RESCUE_CAP + slot] = p;
    }
  }
}

// K5: exact fp32 recompute (value + first-argmax) for rescued rows.
// 4 rows per block; dot split 4-ways over k, coalesced mb streaming.
__global__ __launch_bounds__(256) void k_rescue(const float* __restrict__ ma,
                                                const float* __restrict__ mb,
                                                const int* __restrict__ rescueIdx,
                                                const int* __restrict__ rescueCnt,
                                                float* __restrict__ valA,
                                                int* __restrict__ nodeA) {
  const int bq = blockIdx.x >> 9, rb = blockIdx.x & 511;
  int cnt = min(rescueCnt[bq], RESCUE_CAP);
  int base = rb * 4;
  if (base >= cnt) return;
  int nr = min(4, cnt - base);
  __shared__ float sA[4][128];
  __shared__ int srow[4];
  __shared__ float rv[4][4];
  __shared__ int ri[4][4];
  const int t = threadIdx.x;
  if (t < nr) srow[t] = rescueIdx[bq * RESCUE_CAP + base + t];
  __syncthreads();
  for (int idx = t; idx < nr * 128; idx += 256)
    sA[idx >> 7][idx & 127] = ma[((size_t)bq * NA + srow[idx >> 7]) * MDIM + (idx & 127)];
  __syncthreads();
  const int myc = t >> 2, ks = (t & 3) * 32;
  float best[4];
  int besti[4];
#pragma unroll
  for (int r = 0; r < 4; ++r) { best[r] = -1e30f; besti[r] = 0x7FFFFFFF; }
  for (int c0 = 0; c0 < NA; c0 += 64) {
    int c = c0 + myc;
    const float* bp = mb + ((size_t)bq * NA + c) * MDIM + ks;
    float4 b4[8];
#pragma unroll
    for (int j = 0; j < 8; ++j) b4[j] = *(const float4*)(bp + j * 4);
#pragma unroll
    for (int r = 0; r < 4; ++r) {
      if (r < nr) {
        float d = 0.f;
#pragma unroll
        for (int j = 0; j < 8; ++j) {
          float4 a4 = *(const float4*)&sA[r][ks + j * 4];
          d = fmaf(a4.x, b4[j].x, d);
          d = fmaf(a4.y, b4[j].y, d);
          d = fmaf(a4.z, b4[j].z, d);
          d = fmaf(a4.w, b4[j].w, d);
        }
        d += __shfl_xor(d, 1);
        d += __shfl_xor(d, 2);
        if (d > best[r]) { best[r] = d; besti[r] = c; }
      }
    }
  }
  for (int r = 0; r < nr; ++r) {
    float v = best[r];
    int i1 = besti[r];
    for (int m = 4; m < 64; m <<= 1) {
      float V = __shfl_xor(v, m);
      int I = __shfl_xor(i1, m);
      if (V > v || (V == v && I < i1)) { v = V; i1 = I; }
    }
    if ((t & 63) == 0) { rv[r][t >> 6] = v; ri[r][t >> 6] = i1; }
  }
  __syncthreads();
  if (t == 0) {
    for (int r = 0; r < nr; ++r) {
      float v = rv[r][0];
      int i1 = ri[r][0];
      for (int w2 = 1; w2 < 4; ++w2) {
        float V = rv[r][w2];
        int I = ri[r][w2];
        if (V > v || (V == v && I < i1)) { v = V; i1 = I; }
      }
      valA[(size_t)bq * NA + srow[r]] = v;
      nodeA[(size_t)bq * NA + srow[r]] = i1;
    }
  }
}

// K6: exact top-2048 of final values (bitonic, replicates top_k partition)
__global__ __launch_bounds__(1024) void k_topk(const float* __restrict__ values,
                                               int* __restrict__ sel) {
  __shared__ unsigned long long keys[NA];
  const int b = blockIdx.x, t = threadIdx.x;
  for (int p = t; p < NA; p += 1024) {
    float v = values[(size_t)b * NA + p];
    unsigned u = __float_as_uint(v);
    unsigned mono = u ^ ((u >> 31) ? 0xFFFFFFFFu : 0x80000000u);
    keys[p] = ((unsigned long long)(~mono) << 32) | (unsigned)p;
  }
  __syncthreads();
  for (int k = 2; k <= NA; k <<= 1) {
    for (int j = k >> 1; j > 0; j >>= 1) {
      for (int p = t; p < NA; p += 1024) {
        int q = p ^ j;
        if (q > p) {
          bool up = ((p & k) == 0);
          unsigned long long a = keys[p], c = keys[q];
          if ((a > c) == up) { keys[p] = c; keys[q] = a; }
        }
      }
      __syncthreads();
    }
  }
  for (int p = t; p < NA; p += 1024) {
    int idx = (int)(keys[p] & 0xFFFFFFFFull);
    sel[(size_t)b * NA + idx] = (p < RSEL) ? 1 : 0;
  }
}

// K7: per-destination merge lists (count + atomicExch linked list)
__global__ void k_build(const int* __restrict__ sel, const int* __restrict__ node,
                        int* __restrict__ cnt, int* __restrict__ head,
                        int* __restrict__ nxt) {
  int i = blockIdx.x * 256 + threadIdx.x;
  if (i >= BQ * NA) return;
  int bq = i >> 12, k = i & (NA - 1);
  if (sel[i]) {
    int dst = node[i];
    atomicAdd(&cnt[(size_t)bq * NA + dst], 1);
    nxt[i] = atomicExch(&head[(size_t)bq * NA + dst], k);
  }
}

// K8: mask scan -> new_idx; ownership output (float32). One block per batch.
__global__ __launch_bounds__(1024) void k_scan(const int* __restrict__ sel,
                                               const int* __restrict__ node,
                                               int* __restrict__ newidx,
                                               float* __restrict__ own) {
  __shared__ int ni[NTOK];
  __shared__ int tot[1024];
  const int b = blockIdx.x, t = threadIdx.x;
  const int base = t * 8;
  int kept[8], run = 0;
#pragma unroll
  for (int e = 0; e < 8; ++e) {
    int idx = base + e;
    int kp = ((idx & 1) == 0) ? 1 : (sel[(size_t)b * NA + (idx >> 1)] ? 0 : 1);
    kept[e] = kp;
    run += kp;
  }
  tot[t] = run;
  __syncthreads();
  for (int off = 1; off < 1024; off <<= 1) {
    int v = (t >= off) ? tot[t - off] : 0;
    __syncthreads();
    tot[t] += v;
    __syncthreads();
  }
  int cum = tot[t] - run;
#pragma unroll
  for (int e = 0; e < 8; ++e) {
    cum += kept[e];
    ni[base + e] = cum - 1;
  }
  __syncthreads();
#pragma unroll
  for (int e = 0; e < 8; ++e) {
    int idx = base + e;
    int ow = kept[e] ? ni[idx] : ni[2 * node[(size_t)b * NA + (idx >> 1)]];
    newidx[(size_t)b * NTOK + idx] = ni[idx];
    own[(size_t)b * NTOK + idx] = (float)ow;
  }
}

// K9: assemble x_final f32 (gather merges via linked list, divide, compact)
__global__ __launch_bounds__(128) void k_assemble(const float* __restrict__ X,
                                                  const int* __restrict__ sel,
                                                  const int* __restrict__ newidx,
                                                  const int* __restrict__ cnt,
                                                  const int* __restrict__ head,
                                                  const int* __restrict__ nxt,
                                                  float* __restrict__ out) {
  const int token = blockIdx.x;
  const int bq = token >> 13, tp = token & (NTOK - 1);
  if ((tp & 1) && sel[(size_t)bq * NA + (tp >> 1)]) return;
  const int t = threadIdx.x;
  float4 v = *(const float4*)(X + (size_t)token * CDIM + t * 4);
  if (!(tp & 1)) {
    size_t slot = (size_t)bq * NA + (tp >> 1);
    int c = cnt[slot];
    if (c > 0) {
      int kk = head[slot];
      while (kk >= 0) {
        float4 s = *(const float4*)(X + ((size_t)bq * NTOK + 2 * kk + 1) * CDIM + t * 4);
        v.x += s.x; v.y += s.y; v.z += s.z; v.w += s.w;
        kk = nxt[(size_t)bq * NA + kk];
      }
      float inv = 1.0f / (float)(1 + c);
      v.x *= inv; v.y *= inv; v.z *= inv; v.w *= inv;
    }
  }
  int dst = newidx[(size_t)bq * NTOK + tp];
  *(float4*)(out + ((size_t)bq * NKEEP + dst) * CDIM + t * 4) = v;
}

// ---------------------------------------------------------------------------
extern "C" void kernel_launch(void* const* d_in, const int* in_sizes, int n_in,
                              void* d_out, int out_size, void* d_ws, size_t ws_size,
                              hipStream_t stream) {
  const float* X    = (const float*)d_in[0];
  const float* W    = (const float*)d_in[1];
  const float* bias = (const float*)d_in[2];
  float* out = (float*)d_out;  // f32: x_final (4,6144,512) ++ ownership (4,8192)
  char* ws = (char*)d_ws;

  size_t o = 0;
  float* ma   = (float*)(ws + o); o += (size_t)BQ * NA * MDIM * 4;   // 8 MB
  float* mb   = (float*)(ws + o); o += (size_t)BQ * NA * MDIM * 4;   // 8 MB
  unsigned short* maH = (unsigned short*)(ws + o); o += (size_t)BQ * NA * MDIM * 2;
  unsigned short* maM = (unsigned short*)(ws + o); o += (size_t)BQ * NA * MDIM * 2;
  unsigned short* mbH = (unsigned short*)(ws + o); o += (size_t)BQ * NA * MDIM * 2;
  unsigned short* mbM = (unsigned short*)(ws + o); o += (size_t)BQ * NA * MDIM * 2;
  float* pv1  = (float*)(ws + o); o += (size_t)BQ * 4 * NA * 4;
  int*   pi1  = (int*)(ws + o);   o += (size_t)BQ * 4 * NA * 4;
  float* pv2  = (float*)(ws + o); o += (size_t)BQ * 4 * NA * 4;
  float* valA = (float*)(ws + o); o += (size_t)BQ * NA * 4;
  int*   nodeA= (int*)(ws + o);   o += (size_t)BQ * NA * 4;
  float* gapA = (float*)(ws + o); o += (size_t)BQ * NA * 4;
  int*   sel  = (int*)(ws + o);   o += (size_t)BQ * NA * 4;
  int*   cnt  = (int*)(ws + o);   o += (size_t)BQ * NA * 4;
  int*   head = (int*)(ws + o);   o += (size_t)BQ * NA * 4;
  int*   nxt  = (int*)(ws + o);   o += (size_t)BQ * NA * 4;
  int*   newidx = (int*)(ws + o); o += (size_t)BQ * NTOK * 4;
  int*   rescueCnt = (int*)(ws + o); o += 256;
  int*   rescueIdx = (int*)(ws + o); o += (size_t)BQ * RESCUE_CAP * 4;
  (void)in_sizes; (void)n_in; (void)out_size; (void)ws_size;

  hipMemsetAsync(cnt, 0, (size_t)BQ * NA * 4, stream);
  hipMemsetAsync(head, 0xFF, (size_t)BQ * NA * 4, stream);
  hipMemsetAsync(rescueCnt, 0, 256, stream);

  k_metric<<<256, 256, 0, stream>>>(X, W, bias, ma, mb, maH, maM, mbH, mbM);
  k_scores_mfma<<<512, 256, 0, stream>>>(maH, maM, mbH, mbM, pv1, pi1, pv2);
  k_merge4<<<(BQ * NA + 255) / 256, 256, 0, stream>>>(pv1, pi1, pv2, valA, nodeA, gapA);
  k_mark<<<BQ, 1024, 0, stream>>>(valA, gapA, rescueCnt, rescueIdx);
  k_rescue<<<BQ * 512, 256, 0, stream>>>(ma, mb, rescueIdx, rescueCnt, valA, nodeA);
  k_topk<<<BQ, 1024, 0, stream>>>(valA, sel);
  k_build<<<(BQ * NA + 255) / 256, 256, 0, stream>>>(sel, nodeA, cnt, head, nxt);
  k_scan<<<BQ, 1024, 0, stream>>>(sel, nodeA, newidx, out + (size_t)BQ * NKEEP * CDIM);
  k_assemble<<<BQ * NTOK, 128, 0, stream>>>(X, sel, newidx, cnt, head, nxt, out);
}

// Round 4
// 475.960 us; speedup vs baseline: 1.2831x; 1.2831x over previous
//
#include <hip/hip_runtime.h>
#include <cstdint>
#include <cstddef>

#define BQ    4
#define NTOK  8192
#define CDIM  512
#define MDIM  128
#define NA    4096
#define RSEL  2048
#define NKEEP (NTOK - RSEL)   // 6144
#define RESCUE_CAP 2048
#define GAP_DELTA 2e-4f
#define WIN_TAU   2e-4f

typedef float f32x4 __attribute__((ext_vector_type(4)));
typedef short short8 __attribute__((ext_vector_type(8)));

static __device__ __forceinline__ unsigned short bf16rne(float f) {
  unsigned u = __float_as_uint(f);
  return (unsigned short)((u + 0x7FFFu + ((u >> 16) & 1)) >> 16);
}

// ---------------------------------------------------------------------------
// K1: metric = x @ W^T + b, row-normalize, split even/odd rows into ma/mb
// (fp32) AND emit bf16 hi/mid planes for the MFMA scores kernel.
// ---------------------------------------------------------------------------
__global__ __launch_bounds__(256) void k_metric(const float* __restrict__ X,
                                                const float* __restrict__ W,
                                                const float* __restrict__ bias,
                                                float* __restrict__ ma,
                                                float* __restrict__ mb,
                                                unsigned short* __restrict__ maH,
                                                unsigned short* __restrict__ maM,
                                                unsigned short* __restrict__ mbH,
                                                unsigned short* __restrict__ mbM) {
  __shared__ float ldsA[128 * 128];
  __shared__ float ldsB[128 * 128];
  __shared__ float snorm[128 * 16];
  __shared__ float sinv[128];
  const int t = threadIdx.x;
  const int tok0 = blockIdx.x * 128;
  const int r16 = t & 15, g = t >> 4;

  float acc[8][8];
#pragma unroll
  for (int i = 0; i < 8; ++i)
#pragma unroll
    for (int j = 0; j < 8; ++j) acc[i][j] = 0.f;

  for (int kc = 0; kc < 4; ++kc) {
    __syncthreads();
#pragma unroll
    for (int it = 0; it < 16; ++it) {
      int f = it * 256 + t;
      int row = f >> 5, k4 = f & 31;
      float4 xv = *(const float4*)(X + (size_t)(tok0 + row) * CDIM + kc * 128 + k4 * 4);
      *(float4*)&ldsA[row * 128 + ((k4 ^ (row & 7)) << 2)] = xv;
      float4 wv = *(const float4*)(W + (size_t)row * CDIM + kc * 128 + k4 * 4);
      *(float4*)&ldsB[row * 128 + ((k4 ^ ((row >> 3) & 7)) << 2)] = wv;
    }
    __syncthreads();
#pragma unroll 4
    for (int kq = 0; kq < 32; ++kq) {
      float4 av[8], bv[8];
#pragma unroll
      for (int i = 0; i < 8; ++i) {
        int r = r16 + (i << 4);
        av[i] = *(const float4*)&ldsA[r * 128 + ((kq ^ (r & 7)) << 2)];
      }
#pragma unroll
      for (int j = 0; j < 8; ++j) {
        int c = (g << 3) + j;
        bv[j] = *(const float4*)&ldsB[c * 128 + ((kq ^ ((c >> 3) & 7)) << 2)];
      }
#pragma unroll
      for (int i = 0; i < 8; ++i)
#pragma unroll
        for (int j = 0; j < 8; ++j) {
          acc[i][j] = fmaf(av[i].x, bv[j].x, acc[i][j]);
          acc[i][j] = fmaf(av[i].y, bv[j].y, acc[i][j]);
          acc[i][j] = fmaf(av[i].z, bv[j].z, acc[i][j]);
          acc[i][j] = fmaf(av[i].w, bv[j].w, acc[i][j]);
        }
    }
  }

  float bb[8];
#pragma unroll
  for (int j = 0; j < 8; ++j) bb[j] = bias[(g << 3) + j];
#pragma unroll
  for (int i = 0; i < 8; ++i) {
    float s = 0.f;
#pragma unroll
    for (int j = 0; j < 8; ++j) {
      acc[i][j] += bb[j];
      s = fmaf(acc[i][j], acc[i][j], s);
    }
    snorm[(r16 + (i << 4)) * 16 + g] = s;
  }
  __syncthreads();
  if (t < 128) {
    float s = 0.f;
    for (int q = 0; q < 16; ++q) s += snorm[t * 16 + q];
    sinv[t] = 1.0f / sqrtf(s);
  }
  __syncthreads();
#pragma unroll
  for (int i = 0; i < 8; ++i) {
    int r = r16 + (i << 4);
    int tokg = tok0 + r;
    float inv = sinv[r];
    int bq = tokg >> 13, pos = tokg & (NTOK - 1);
    size_t eidx = ((size_t)bq * NA + (pos >> 1)) * MDIM + (g << 3);
    float vv[8];
#pragma unroll
    for (int j = 0; j < 8; ++j) vv[j] = acc[i][j] * inv;
    float* dst = ((pos & 1) ? mb : ma) + eidx;
    *(float4*)dst = make_float4(vv[0], vv[1], vv[2], vv[3]);
    *(float4*)(dst + 4) = make_float4(vv[4], vv[5], vv[6], vv[7]);
    unsigned hB[8], mB[8];
#pragma unroll
    for (int j = 0; j < 8; ++j) {
      hB[j] = bf16rne(vv[j]);
      mB[j] = bf16rne(vv[j] - __uint_as_float(hB[j] << 16));
    }
    uint4 hw, mw;
    hw.x = hB[0] | (hB[1] << 16); hw.y = hB[2] | (hB[3] << 16);
    hw.z = hB[4] | (hB[5] << 16); hw.w = hB[6] | (hB[7] << 16);
    mw.x = mB[0] | (mB[1] << 16); mw.y = mB[2] | (mB[3] << 16);
    mw.z = mB[4] | (mB[5] << 16); mw.w = mB[6] | (mB[7] << 16);
    *(uint4*)(((pos & 1) ? mbH : maH) + eidx) = hw;
    *(uint4*)(((pos & 1) ? mbM : maM) + eidx) = mw;
  }
}

// ---------------------------------------------------------------------------
// K2: scores via split-bf16 MFMA. score ~= hi*hi + hi*mid + mid*hi.
// Block: 128 a-rows x 1024 c (csplit quarter), 16 c-chunks of 64.
// A (hi+mid, K=128) in registers per wave; B chunks double-buffered in LDS
// via global_load_lds with pre-swizzled source. Tracks per-row top-2 + argmax.
// grid = 4 bq x 32 atiles x 4 csplits = 512 blocks, 256 thr.
// ---------------------------------------------------------------------------
__global__ __launch_bounds__(256, 2) void k_scores_mfma(
    const unsigned short* __restrict__ maH, const unsigned short* __restrict__ maM,
    const unsigned short* __restrict__ mbH, const unsigned short* __restrict__ mbM,
    float* __restrict__ pv1, int* __restrict__ pi1, float* __restrict__ pv2) {
  __shared__ __align__(16) char ldsB[65536];  // [buf2][plane2][64c][128k bf16], XOR-swizzled
  const int t = threadIdx.x;
  const int bid = blockIdx.x;
  const int bq = bid >> 7, rem = bid & 127, at = rem >> 2, cs = rem & 3;
  const int a0 = at * 128;
  const int l = t & 63, w = t >> 6;

  // A fragments (K=128 = 4 chunks of 32), hi+mid planes, 32 rows per wave.
  short8 aH[2][4], aM[2][4];
#pragma unroll
  for (int rf = 0; rf < 2; ++rf)
#pragma unroll
    for (int kc = 0; kc < 4; ++kc) {
      size_t aidx = ((size_t)bq * NA + a0 + w * 32 + rf * 16 + (l & 15)) * MDIM
                    + kc * 32 + ((l >> 4) << 3);
      aH[rf][kc] = *(const short8*)(maH + aidx);
      aM[rf][kc] = *(const short8*)(maM + aidx);
    }

  const unsigned short* bplane = (w >> 1) ? mbM : mbH;

  // stage chunk ch2 into buffer bufn: 2048 slots x 16B, wave w covers 512.
  auto stage = [&](int ch2, int bufn) {
    const int c0s = cs * 1024 + ch2 * 64;
#pragma unroll
    for (int j = 0; j < 8; ++j) {
      int cl = (w & 1) * 32 + j * 4 + (l >> 4);
      int ks16 = (l & 15) << 4;
      const char* src = (const char*)bplane
          + (((size_t)bq * NA + c0s + cl) << 8) + (ks16 ^ ((cl & 7) << 4));
      char* dst = ldsB + bufn * 32768 + (w * 512 + j * 64) * 16;
      __builtin_amdgcn_global_load_lds(
          (const __attribute__((address_space(1))) void*)src,
          (__attribute__((address_space(3))) void*)dst, 16, 0, 0);
    }
  };

  float bv1[8], bv2[8];
  int bi1[8];
#pragma unroll
  for (int s = 0; s < 8; ++s) { bv1[s] = -1e30f; bv2[s] = -1e30f; bi1[s] = 0x7FFFFFFF; }

  stage(0, 0);
  __syncthreads();

  int buf = 0;
  for (int ch = 0; ch < 16; ++ch) {
    if (ch + 1 < 16) stage(ch + 1, buf ^ 1);

    f32x4 acc1[2][4], acc2[2][4];
#pragma unroll
    for (int rf = 0; rf < 2; ++rf)
#pragma unroll
      for (int cf = 0; cf < 4; ++cf) { acc1[rf][cf] = 0.f; acc2[rf][cf] = 0.f; }

    const char* base = ldsB + buf * 32768;
#pragma unroll
    for (int kc = 0; kc < 4; ++kc) {
#pragma unroll
      for (int cf = 0; cf < 4; ++cf) {
        int coff = cf * 16 + (l & 15);
        int kbyte = (kc * 64 + ((l >> 4) << 4)) ^ ((coff & 7) << 4);
        short8 bh = *(const short8*)(base + coff * 256 + kbyte);
        short8 bm = *(const short8*)(base + 16384 + coff * 256 + kbyte);
#pragma unroll
        for (int rf = 0; rf < 2; ++rf) {
          acc1[rf][cf] = __builtin_amdgcn_mfma_f32_16x16x32_bf16(aH[rf][kc], bh, acc1[rf][cf], 0, 0, 0);
          acc2[rf][cf] = __builtin_amdgcn_mfma_f32_16x16x32_bf16(aH[rf][kc], bm, acc2[rf][cf], 0, 0, 0);
          acc2[rf][cf] = __builtin_amdgcn_mfma_f32_16x16x32_bf16(aM[rf][kc], bh, acc2[rf][cf], 0, 0, 0);
        }
      }
    }

    const int cbase = cs * 1024 + ch * 64;
#pragma unroll
    for (int rf = 0; rf < 2; ++rf)
#pragma unroll
      for (int cf = 0; cf < 4; ++cf) {
        int cg = cbase + cf * 16 + (l & 15);
        f32x4 v4 = acc1[rf][cf] + acc2[rf][cf];
#pragma unroll
        for (int r2 = 0; r2 < 4; ++r2) {
          float v = v4[r2];
          int s = rf * 4 + r2;
          if (v > bv1[s]) { bv2[s] = bv1[s]; bv1[s] = v; bi1[s] = cg; }
          else if (v > bv2[s]) bv2[s] = v;
        }
      }
    __syncthreads();
    buf ^= 1;
  }

  // cross-lane top2 reduce over the 16 cols sharing each row, then write.
#pragma unroll
  for (int s = 0; s < 8; ++s) {
    float v1 = bv1[s], v2 = bv2[s];
    int i1 = bi1[s];
#pragma unroll
    for (int m = 1; m < 16; m <<= 1) {
      float V1 = __shfl_xor(v1, m);
      int I1 = __shfl_xor(i1, m);
      float V2 = __shfl_xor(v2, m);
      bool take = (V1 > v1) || (V1 == v1 && I1 < i1);
      float lose = take ? v1 : V1;
      if (take) { v1 = V1; i1 = I1; }
      v2 = fmaxf(fmaxf(v2, V2), lose);
    }
    if ((l & 15) == s) {
      int row = a0 + w * 32 + (s >> 2) * 16 + ((l >> 4) << 2) + (s & 3);
      size_t off = ((size_t)(bq * 4 + cs)) * NA + row;
      pv1[off] = v1; pi1[off] = i1; pv2[off] = v2;
    }
  }
}

// K3: merge the 4 csplit partials -> value, node, gap
__global__ void k_merge4(const float* __restrict__ pv1, const int* __restrict__ pi1,
                         const float* __restrict__ pv2,
                         float* __restrict__ valA, int* __restrict__ nodeA,
                         float* __restrict__ gapA) {
  int i = blockIdx.x * 256 + threadIdx.x;
  if (i >= BQ * NA) return;
  int bq = i >> 12, row = i & (NA - 1);
  float v1 = -1e30f, v2 = -1e30f;
  int i1 = 0x7FFFFFFF;
#pragma unroll
  for (int cspl = 0; cspl < 4; ++cspl) {
    size_t o = ((size_t)(bq * 4 + cspl)) * NA + row;
    float V1 = pv1[o], V2 = pv2[o];
    int I1 = pi1[o];
    bool take = (V1 > v1) || (V1 == v1 && I1 < i1);
    float lose = take ? v1 : V1;
    if (take) { v1 = V1; i1 = I1; }
    v2 = fmaxf(fmaxf(v2, V2), lose);
  }
  valA[i] = v1; nodeA[i] = i1; gapA[i] = v1 - v2;
}

// K4: per-batch: sort approx values, find rank-2048 value vb, mark+compact
// rescue rows (top-2 gap < delta OR |v - vb| <= tau).
__global__ __launch_bounds__(1024) void k_mark(const float* __restrict__ valA,
                                               const float* __restrict__ gapA,
                                               int* __restrict__ rescueCnt,
                                               int* __restrict__ rescueIdx) {
  __shared__ unsigned long long keys[NA];
  __shared__ float vbS;
  const int b = blockIdx.x, t = threadIdx.x;
  for (int p = t; p < NA; p += 1024) {
    float v = valA[(size_t)b * NA + p];
    unsigned u = __float_as_uint(v);
    unsigned mono = u ^ ((u >> 31) ? 0xFFFFFFFFu : 0x80000000u);
    keys[p] = ((unsigned long long)(~mono) << 32) | (unsigned)p;
  }
  __syncthreads();
  for (int k = 2; k <= NA; k <<= 1) {
    for (int j = k >> 1; j > 0; j >>= 1) {
      for (int p = t; p < NA; p += 1024) {
        int q = p ^ j;
        if (q > p) {
          bool up = ((p & k) == 0);
          unsigned long long a = keys[p], c = keys[q];
          if ((a > c) == up) { keys[p] = c; keys[q] = a; }
        }
      }
      __syncthreads();
    }
  }
  if (t == 0) {
    unsigned mono = ~(unsigned)(keys[RSEL - 1] >> 32);
    unsigned u = (mono >> 31) ? (mono ^ 0x80000000u) : ~mono;
    vbS = __uint_as_float(u);
  }
  __syncthreads();
  float vb = vbS;
  for (int p = t; p < NA; p += 1024) {
    size_t o = (size_t)b * NA + p;
    if (gapA[o] < GAP_DELTA || fabsf(valA[o] - vb) <= WIN_TAU) {
      int slot = atomicAdd(&rescueCnt[b], 1);
      if (slot < RESCUE_CAP) rescueIdx[b * RESCUE_CAP + slot] = p;
    }
  }
}

// K5: exact fp32 recompute (value + first-argmax) for rescued rows.
// ONE row per block, 256 threads; thread owns col c = it*256+t (ascending),
// full-K dot with 32 independent float4 loads + 4-way split accumulators.
__global__ __launch_bounds__(256) void k_rescue(const float* __restrict__ ma,
                                                const float* __restrict__ mb,
                                                const int* __restrict__ rescueIdx,
                                                const int* __restrict__ rescueCnt,
                                                float* __restrict__ valA,
                                                int* __restrict__ nodeA) {
  const int bq = blockIdx.x >> 7;          // grid = BQ*128
  const int rb0 = blockIdx.x & 127;
  const int cnt = min(rescueCnt[bq], RESCUE_CAP);
  const int t = threadIdx.x;
  __shared__ float sA[128];
  __shared__ float wvS[4];
  __shared__ int   wiS[4];
  for (int slot = rb0; slot < cnt; slot += 128) {
    const int row = rescueIdx[bq * RESCUE_CAP + slot];
    __syncthreads();                        // protect sA/wvS reuse across slots
    if (t < 128) sA[t] = ma[((size_t)bq * NA + row) * MDIM + t];
    __syncthreads();
    float best = -1e30f;
    int besti = 0x7FFFFFFF;
    for (int it = 0; it < 16; ++it) {
      const int c = it * 256 + t;
      const float* bp = mb + ((size_t)bq * NA + c) * MDIM;
      float d0 = 0.f, d1 = 0.f, d2 = 0.f, d3 = 0.f;
#pragma unroll
      for (int j = 0; j < 8; ++j) {
        float4 b0 = *(const float4*)(bp + j * 16 + 0);
        float4 b1 = *(const float4*)(bp + j * 16 + 4);
        float4 b2 = *(const float4*)(bp + j * 16 + 8);
        float4 b3 = *(const float4*)(bp + j * 16 + 12);
        const float4 a0 = *(const float4*)&sA[j * 16 + 0];
        const float4 a1 = *(const float4*)&sA[j * 16 + 4];
        const float4 a2 = *(const float4*)&sA[j * 16 + 8];
        const float4 a3 = *(const float4*)&sA[j * 16 + 12];
        d0 = fmaf(a0.x, b0.x, d0); d0 = fmaf(a0.y, b0.y, d0);
        d0 = fmaf(a0.z, b0.z, d0); d0 = fmaf(a0.w, b0.w, d0);
        d1 = fmaf(a1.x, b1.x, d1); d1 = fmaf(a1.y, b1.y, d1);
        d1 = fmaf(a1.z, b1.z, d1); d1 = fmaf(a1.w, b1.w, d1);
        d2 = fmaf(a2.x, b2.x, d2); d2 = fmaf(a2.y, b2.y, d2);
        d2 = fmaf(a2.z, b2.z, d2); d2 = fmaf(a2.w, b2.w, d2);
        d3 = fmaf(a3.x, b3.x, d3); d3 = fmaf(a3.y, b3.y, d3);
        d3 = fmaf(a3.z, b3.z, d3); d3 = fmaf(a3.w, b3.w, d3);
      }
      const float d = (d0 + d1) + (d2 + d3);
      if (d > best) { best = d; besti = c; }
    }
    float v = best;
    int i1 = besti;
#pragma unroll
    for (int m = 1; m < 64; m <<= 1) {
      float V = __shfl_xor(v, m);
      int I = __shfl_xor(i1, m);
      if (V > v || (V == v && I < i1)) { v = V; i1 = I; }
    }
    if ((t & 63) == 0) { wvS[t >> 6] = v; wiS[t >> 6] = i1; }
    __syncthreads();
    if (t == 0) {
      for (int w2 = 1; w2 < 4; ++w2) {
        if (wvS[w2] > v || (wvS[w2] == v && wiS[w2] < i1)) { v = wvS[w2]; i1 = wiS[w2]; }
      }
      valA[(size_t)bq * NA + row] = v;
      nodeA[(size_t)bq * NA + row] = i1;
    }
  }
}

// K6: exact top-2048 of final values (bitonic, replicates top_k partition)
__global__ __launch_bounds__(1024) void k_topk(const float* __restrict__ values,
                                               int* __restrict__ sel) {
  __shared__ unsigned long long keys[NA];
  const int b = blockIdx.x, t = threadIdx.x;
  for (int p = t; p < NA; p += 1024) {
    float v = values[(size_t)b * NA + p];
    unsigned u = __float_as_uint(v);
    unsigned mono = u ^ ((u >> 31) ? 0xFFFFFFFFu : 0x80000000u);
    keys[p] = ((unsigned long long)(~mono) << 32) | (unsigned)p;
  }
  __syncthreads();
  for (int k = 2; k <= NA; k <<= 1) {
    for (int j = k >> 1; j > 0; j >>= 1) {
      for (int p = t; p < NA; p += 1024) {
        int q = p ^ j;
        if (q > p) {
          bool up = ((p & k) == 0);
          unsigned long long a = keys[p], c = keys[q];
          if ((a > c) == up) { keys[p] = c; keys[q] = a; }
        }
      }
      __syncthreads();
    }
  }
  for (int p = t; p < NA; p += 1024) {
    int idx = (int)(keys[p] & 0xFFFFFFFFull);
    sel[(size_t)b * NA + idx] = (p < RSEL) ? 1 : 0;
  }
}

// K7: per-destination merge lists (count + atomicExch linked list)
__global__ void k_build(const int* __restrict__ sel, const int* __restrict__ node,
                        int* __restrict__ cnt, int* __restrict__ head,
                        int* __restrict__ nxt) {
  int i = blockIdx.x * 256 + threadIdx.x;
  if (i >= BQ * NA) return;
  int bq = i >> 12, k = i & (NA - 1);
  if (sel[i]) {
    int dst = node[i];
    atomicAdd(&cnt[(size_t)bq * NA + dst], 1);
    nxt[i] = atomicExch(&head[(size_t)bq * NA + dst], k);
  }
}

// K8: mask scan -> new_idx; ownership output (float32). One block per batch.
__global__ __launch_bounds__(1024) void k_scan(const int* __restrict__ sel,
                                               const int* __restrict__ node,
                                               int* __restrict__ newidx,
                                               float* __restrict__ own) {
  __shared__ int ni[NTOK];
  __shared__ int tot[1024];
  const int b = blockIdx.x, t = threadIdx.x;
  const int base = t * 8;
  int kept[8], run = 0;
#pragma unroll
  for (int e = 0; e < 8; ++e) {
    int idx = base + e;
    int kp = ((idx & 1) == 0) ? 1 : (sel[(size_t)b * NA + (idx >> 1)] ? 0 : 1);
    kept[e] = kp;
    run += kp;
  }
  tot[t] = run;
  __syncthreads();
  for (int off = 1; off < 1024; off <<= 1) {
    int v = (t >= off) ? tot[t - off] : 0;
    __syncthreads();
    tot[t] += v;
    __syncthreads();
  }
  int cum = tot[t] - run;
#pragma unroll
  for (int e = 0; e < 8; ++e) {
    cum += kept[e];
    ni[base + e] = cum - 1;
  }
  __syncthreads();
#pragma unroll
  for (int e = 0; e < 8; ++e) {
    int idx = base + e;
    int ow = kept[e] ? ni[idx] : ni[2 * node[(size_t)b * NA + (idx >> 1)]];
    newidx[(size_t)b * NTOK + idx] = ni[idx];
    own[(size_t)b * NTOK + idx] = (float)ow;
  }
}

// K9: assemble x_final f32 (gather merges via linked list, divide, compact)
__global__ __launch_bounds__(128) void k_assemble(const float* __restrict__ X,
                                                  const int* __restrict__ sel,
                                                  const int* __restrict__ newidx,
                                                  const int* __restrict__ cnt,
                                                  const int* __restrict__ head,
                                                  const int* __restrict__ nxt,
                                                  float* __restrict__ out) {
  const int token = blockIdx.x;
  const int bq = token >> 13, tp = token & (NTOK - 1);
  if ((tp & 1) && sel[(size_t)bq * NA + (tp >> 1)]) return;
  const int t = threadIdx.x;
  float4 v = *(const float4*)(X + (size_t)token * CDIM + t * 4);
  if (!(tp & 1)) {
    size_t slot = (size_t)bq * NA + (tp >> 1);
    int c = cnt[slot];
    if (c > 0) {
      int kk = head[slot];
      while (kk >= 0) {
        float4 s = *(const float4*)(X + ((size_t)bq * NTOK + 2 * kk + 1) * CDIM + t * 4);
        v.x += s.x; v.y += s.y; v.z += s.z; v.w += s.w;
        kk = nxt[(size_t)bq * NA + kk];
      }
      float inv = 1.0f / (float)(1 + c);
      v.x *= inv; v.y *= inv; v.z *= inv; v.w *= inv;
    }
  }
  int dst = newidx[(size_t)bq * NTOK + tp];
  *(float4*)(out + ((size_t)bq * NKEEP + dst) * CDIM + t * 4) = v;
}

// ---------------------------------------------------------------------------
extern "C" void kernel_launch(void* const* d_in, const int* in_sizes, int n_in,
                              void* d_out, int out_size, void* d_ws, size_t ws_size,
                              hipStream_t stream) {
  const float* X    = (const float*)d_in[0];
  const float* W    = (const float*)d_in[1];
  const float* bias = (const float*)d_in[2];
  float* out = (float*)d_out;  // f32: x_final (4,6144,512) ++ ownership (4,8192)
  char* ws = (char*)d_ws;

  size_t o = 0;
  float* ma   = (float*)(ws + o); o += (size_t)BQ * NA * MDIM * 4;   // 8 MB
  float* mb   = (float*)(ws + o); o += (size_t)BQ * NA * MDIM * 4;   // 8 MB
  unsigned short* maH = (unsigned short*)(ws + o); o += (size_t)BQ * NA * MDIM * 2;
  unsigned short* maM = (unsigned short*)(ws + o); o += (size_t)BQ * NA * MDIM * 2;
  unsigned short* mbH = (unsigned short*)(ws + o); o += (size_t)BQ * NA * MDIM * 2;
  unsigned short* mbM = (unsigned short*)(ws + o); o += (size_t)BQ * NA * MDIM * 2;
  float* pv1  = (float*)(ws + o); o += (size_t)BQ * 4 * NA * 4;
  int*   pi1  = (int*)(ws + o);   o += (size_t)BQ * 4 * NA * 4;
  float* pv2  = (float*)(ws + o); o += (size_t)BQ * 4 * NA * 4;
  float* valA = (float*)(ws + o); o += (size_t)BQ * NA * 4;
  int*   nodeA= (int*)(ws + o);   o += (size_t)BQ * NA * 4;
  float* gapA = (float*)(ws + o); o += (size_t)BQ * NA * 4;
  int*   sel  = (int*)(ws + o);   o += (size_t)BQ * NA * 4;
  int*   cnt  = (int*)(ws + o);   o += (size_t)BQ * NA * 4;
  int*   head = (int*)(ws + o);   o += (size_t)BQ * NA * 4;
  int*   nxt  = (int*)(ws + o);   o += (size_t)BQ * NA * 4;
  int*   newidx = (int*)(ws + o); o += (size_t)BQ * NTOK * 4;
  int*   rescueCnt = (int*)(ws + o); o += 256;
  int*   rescueIdx = (int*)(ws + o); o += (size_t)BQ * RESCUE_CAP * 4;
  (void)in_sizes; (void)n_in; (void)out_size; (void)ws_size;

  hipMemsetAsync(cnt, 0, (size_t)BQ * NA * 4, stream);
  hipMemsetAsync(head, 0xFF, (size_t)BQ * NA * 4, stream);
  hipMemsetAsync(rescueCnt, 0, 256, stream);

  k_metric<<<256, 256, 0, stream>>>(X, W, bias, ma, mb, maH, maM, mbH, mbM);
  k_scores_mfma<<<512, 256, 0, stream>>>(maH, maM, mbH, mbM, pv1, pi1, pv2);
  k_merge4<<<(BQ * NA + 255) / 256, 256, 0, stream>>>(pv1, pi1, pv2, valA, nodeA, gapA);
  k_mark<<<BQ, 1024, 0, stream>>>(valA, gapA, rescueCnt, rescueIdx);
  k_rescue<<<BQ * 128, 256, 0, stream>>>(ma, mb, rescueIdx, rescueCnt, valA, nodeA);
  k_topk<<<BQ, 1024, 0, stream>>>(valA, sel);
  k_build<<<(BQ * NA + 255) / 256, 256, 0, stream>>>(sel, nodeA, cnt, head, nxt);
  k_scan<<<BQ, 1024, 0, stream>>>(sel, nodeA, newidx, out + (size_t)BQ * NKEEP * CDIM);
  k_assemble<<<BQ * NTOK, 128, 0, stream>>>(X, sel, newidx, cnt, head, nxt, out);
}

// Round 5
// 413.697 us; speedup vs baseline: 1.4762x; 1.1505x over previous
//
#include <hip/hip_runtime.h>
#include <cstdint>
#include <cstddef>

#define BQ    4
#define NTOK  8192
#define CDIM  512
#define MDIM  128
#define NA    4096
#define RSEL  2048
#define NKEEP (NTOK - RSEL)   // 6144
#define RESCUE_CAP 2048
#define GAP_DELTA 2e-4f
#define WIN_TAU   2e-4f

typedef float f32x4 __attribute__((ext_vector_type(4)));
typedef short short8 __attribute__((ext_vector_type(8)));

static __device__ __forceinline__ unsigned short bf16rne(float f) {
  unsigned u = __float_as_uint(f);
  return (unsigned short)((u + 0x7FFFu + ((u >> 16) & 1)) >> 16);
}

// ---------------------------------------------------------------------------
// K1: metric = x @ W^T + b, row-normalize, split even/odd rows into ma/mb
// (fp32) AND emit bf16 hi/mid planes. 512 blocks x 64-token tiles; K-chunk 64
// keeps LDS at 52.5 KB -> 2+ blocks/CU (round-4 version was 136 KB -> 1/CU).
// ---------------------------------------------------------------------------
__global__ __launch_bounds__(256) void k_metric(const float* __restrict__ X,
                                                const float* __restrict__ W,
                                                const float* __restrict__ bias,
                                                float* __restrict__ ma,
                                                float* __restrict__ mb,
                                                unsigned short* __restrict__ maH,
                                                unsigned short* __restrict__ maM,
                                                unsigned short* __restrict__ mbH,
                                                unsigned short* __restrict__ mbM) {
  __shared__ float ldsA[64 * 64];    // 16 KB
  __shared__ float ldsB[128 * 64];   // 32 KB
  __shared__ float snorm[64 * 16];   // 4 KB
  __shared__ float sinv[64];
  const int t = threadIdx.x;
  const int tok0 = blockIdx.x * 64;
  const int r16 = t & 15, g = t >> 4;

  float acc[4][8];
#pragma unroll
  for (int i = 0; i < 4; ++i)
#pragma unroll
    for (int j = 0; j < 8; ++j) acc[i][j] = 0.f;

  for (int kc = 0; kc < 8; ++kc) {
    __syncthreads();
#pragma unroll
    for (int it = 0; it < 4; ++it) {   // A: 64 rows x 16 slots
      int f = it * 256 + t;
      int row = f >> 4, k4 = f & 15;
      float4 xv = *(const float4*)(X + (size_t)(tok0 + row) * CDIM + kc * 64 + k4 * 4);
      *(float4*)&ldsA[row * 64 + ((k4 ^ (row & 15)) << 2)] = xv;
    }
#pragma unroll
    for (int it = 0; it < 8; ++it) {   // B: 128 rows x 16 slots
      int f = it * 256 + t;
      int row = f >> 4, k4 = f & 15;
      float4 wv = *(const float4*)(W + (size_t)row * CDIM + kc * 64 + k4 * 4);
      *(float4*)&ldsB[row * 64 + ((k4 ^ (row & 15)) << 2)] = wv;
    }
    __syncthreads();
#pragma unroll 4
    for (int kq = 0; kq < 16; ++kq) {
      float4 av[4], bv[8];
#pragma unroll
      for (int i = 0; i < 4; ++i) {
        int r = r16 + (i << 4);
        av[i] = *(const float4*)&ldsA[r * 64 + ((kq ^ (r & 15)) << 2)];
      }
#pragma unroll
      for (int j = 0; j < 8; ++j) {
        int cc = (g << 3) + j;
        bv[j] = *(const float4*)&ldsB[cc * 64 + ((kq ^ (cc & 15)) << 2)];
      }
#pragma unroll
      for (int i = 0; i < 4; ++i)
#pragma unroll
        for (int j = 0; j < 8; ++j) {
          acc[i][j] = fmaf(av[i].x, bv[j].x, acc[i][j]);
          acc[i][j] = fmaf(av[i].y, bv[j].y, acc[i][j]);
          acc[i][j] = fmaf(av[i].z, bv[j].z, acc[i][j]);
          acc[i][j] = fmaf(av[i].w, bv[j].w, acc[i][j]);
        }
    }
  }

  float bb[8];
#pragma unroll
  for (int j = 0; j < 8; ++j) bb[j] = bias[(g << 3) + j];
#pragma unroll
  for (int i = 0; i < 4; ++i) {
    float s = 0.f;
#pragma unroll
    for (int j = 0; j < 8; ++j) {
      acc[i][j] += bb[j];
      s = fmaf(acc[i][j], acc[i][j], s);
    }
    snorm[(r16 + (i << 4)) * 16 + g] = s;
  }
  __syncthreads();
  if (t < 64) {
    float s = 0.f;
    for (int q = 0; q < 16; ++q) s += snorm[t * 16 + q];
    sinv[t] = 1.0f / sqrtf(s);
  }
  __syncthreads();
#pragma unroll
  for (int i = 0; i < 4; ++i) {
    int r = r16 + (i << 4);
    int tokg = tok0 + r;
    float inv = sinv[r];
    int bq = tokg >> 13, pos = tokg & (NTOK - 1);
    size_t eidx = ((size_t)bq * NA + (pos >> 1)) * MDIM + (g << 3);
    float vv[8];
#pragma unroll
    for (int j = 0; j < 8; ++j) vv[j] = acc[i][j] * inv;
    float* dst = ((pos & 1) ? mb : ma) + eidx;
    *(float4*)dst = make_float4(vv[0], vv[1], vv[2], vv[3]);
    *(float4*)(dst + 4) = make_float4(vv[4], vv[5], vv[6], vv[7]);
    unsigned hB[8], mB[8];
#pragma unroll
    for (int j = 0; j < 8; ++j) {
      hB[j] = bf16rne(vv[j]);
      mB[j] = bf16rne(vv[j] - __uint_as_float(hB[j] << 16));
    }
    uint4 hw, mw;
    hw.x = hB[0] | (hB[1] << 16); hw.y = hB[2] | (hB[3] << 16);
    hw.z = hB[4] | (hB[5] << 16); hw.w = hB[6] | (hB[7] << 16);
    mw.x = mB[0] | (mB[1] << 16); mw.y = mB[2] | (mB[3] << 16);
    mw.z = mB[4] | (mB[5] << 16); mw.w = mB[6] | (mB[7] << 16);
    *(uint4*)(((pos & 1) ? mbH : maH) + eidx) = hw;
    *(uint4*)(((pos & 1) ? mbM : maM) + eidx) = mw;
  }
}

// ---------------------------------------------------------------------------
// K2: scores via split-bf16 MFMA (hi*hi + hi*mid + mid*hi), per-row top-2.
// ---------------------------------------------------------------------------
__global__ __launch_bounds__(256, 2) void k_scores_mfma(
    const unsigned short* __restrict__ maH, const unsigned short* __restrict__ maM,
    const unsigned short* __restrict__ mbH, const unsigned short* __restrict__ mbM,
    float* __restrict__ pv1, int* __restrict__ pi1, float* __restrict__ pv2) {
  __shared__ __align__(16) char ldsB[65536];
  const int t = threadIdx.x;
  const int bid = blockIdx.x;
  const int bq = bid >> 7, rem = bid & 127, at = rem >> 2, cs = rem & 3;
  const int a0 = at * 128;
  const int l = t & 63, w = t >> 6;

  short8 aH[2][4], aM[2][4];
#pragma unroll
  for (int rf = 0; rf < 2; ++rf)
#pragma unroll
    for (int kc = 0; kc < 4; ++kc) {
      size_t aidx = ((size_t)bq * NA + a0 + w * 32 + rf * 16 + (l & 15)) * MDIM
                    + kc * 32 + ((l >> 4) << 3);
      aH[rf][kc] = *(const short8*)(maH + aidx);
      aM[rf][kc] = *(const short8*)(maM + aidx);
    }

  const unsigned short* bplane = (w >> 1) ? mbM : mbH;

  auto stage = [&](int ch2, int bufn) {
    const int c0s = cs * 1024 + ch2 * 64;
#pragma unroll
    for (int j = 0; j < 8; ++j) {
      int cl = (w & 1) * 32 + j * 4 + (l >> 4);
      int ks16 = (l & 15) << 4;
      const char* src = (const char*)bplane
          + (((size_t)bq * NA + c0s + cl) << 8) + (ks16 ^ ((cl & 7) << 4));
      char* dst = ldsB + bufn * 32768 + (w * 512 + j * 64) * 16;
      __builtin_amdgcn_global_load_lds(
          (const __attribute__((address_space(1))) void*)src,
          (__attribute__((address_space(3))) void*)dst, 16, 0, 0);
    }
  };

  float bv1[8], bv2[8];
  int bi1[8];
#pragma unroll
  for (int s = 0; s < 8; ++s) { bv1[s] = -1e30f; bv2[s] = -1e30f; bi1[s] = 0x7FFFFFFF; }

  stage(0, 0);
  __syncthreads();

  int buf = 0;
  for (int ch = 0; ch < 16; ++ch) {
    if (ch + 1 < 16) stage(ch + 1, buf ^ 1);

    f32x4 acc1[2][4], acc2[2][4];
#pragma unroll
    for (int rf = 0; rf < 2; ++rf)
#pragma unroll
      for (int cf = 0; cf < 4; ++cf) { acc1[rf][cf] = 0.f; acc2[rf][cf] = 0.f; }

    const char* base = ldsB + buf * 32768;
#pragma unroll
    for (int kc = 0; kc < 4; ++kc) {
#pragma unroll
      for (int cf = 0; cf < 4; ++cf) {
        int coff = cf * 16 + (l & 15);
        int kbyte = (kc * 64 + ((l >> 4) << 4)) ^ ((coff & 7) << 4);
        short8 bh = *(const short8*)(base + coff * 256 + kbyte);
        short8 bm = *(const short8*)(base + 16384 + coff * 256 + kbyte);
#pragma unroll
        for (int rf = 0; rf < 2; ++rf) {
          acc1[rf][cf] = __builtin_amdgcn_mfma_f32_16x16x32_bf16(aH[rf][kc], bh, acc1[rf][cf], 0, 0, 0);
          acc2[rf][cf] = __builtin_amdgcn_mfma_f32_16x16x32_bf16(aH[rf][kc], bm, acc2[rf][cf], 0, 0, 0);
          acc2[rf][cf] = __builtin_amdgcn_mfma_f32_16x16x32_bf16(aM[rf][kc], bh, acc2[rf][cf], 0, 0, 0);
        }
      }
    }

    const int cbase = cs * 1024 + ch * 64;
#pragma unroll
    for (int rf = 0; rf < 2; ++rf)
#pragma unroll
      for (int cf = 0; cf < 4; ++cf) {
        int cg = cbase + cf * 16 + (l & 15);
        f32x4 v4 = acc1[rf][cf] + acc2[rf][cf];
#pragma unroll
        for (int r2 = 0; r2 < 4; ++r2) {
          float v = v4[r2];
          int s = rf * 4 + r2;
          if (v > bv1[s]) { bv2[s] = bv1[s]; bv1[s] = v; bi1[s] = cg; }
          else if (v > bv2[s]) bv2[s] = v;
        }
      }
    __syncthreads();
    buf ^= 1;
  }

#pragma unroll
  for (int s = 0; s < 8; ++s) {
    float v1 = bv1[s], v2 = bv2[s];
    int i1 = bi1[s];
#pragma unroll
    for (int m = 1; m < 16; m <<= 1) {
      float V1 = __shfl_xor(v1, m);
      int I1 = __shfl_xor(i1, m);
      float V2 = __shfl_xor(v2, m);
      bool take = (V1 > v1) || (V1 == v1 && I1 < i1);
      float lose = take ? v1 : V1;
      if (take) { v1 = V1; i1 = I1; }
      v2 = fmaxf(fmaxf(v2, V2), lose);
    }
    if ((l & 15) == s) {
      int row = a0 + w * 32 + (s >> 2) * 16 + ((l >> 4) << 2) + (s & 3);
      size_t off = ((size_t)(bq * 4 + cs)) * NA + row;
      pv1[off] = v1; pi1[off] = i1; pv2[off] = v2;
    }
  }
}

// K3: merge the 4 csplit partials -> value, node, gap
__global__ void k_merge4(const float* __restrict__ pv1, const int* __restrict__ pi1,
                         const float* __restrict__ pv2,
                         float* __restrict__ valA, int* __restrict__ nodeA,
                         float* __restrict__ gapA) {
  int i = blockIdx.x * 256 + threadIdx.x;
  if (i >= BQ * NA) return;
  int bq = i >> 12, row = i & (NA - 1);
  float v1 = -1e30f, v2 = -1e30f;
  int i1 = 0x7FFFFFFF;
#pragma unroll
  for (int cspl = 0; cspl < 4; ++cspl) {
    size_t o = ((size_t)(bq * 4 + cspl)) * NA + row;
    float V1 = pv1[o], V2 = pv2[o];
    int I1 = pi1[o];
    bool take = (V1 > v1) || (V1 == v1 && I1 < i1);
    float lose = take ? v1 : V1;
    if (take) { v1 = V1; i1 = I1; }
    v2 = fmaxf(fmaxf(v2, V2), lose);
  }
  valA[i] = v1; nodeA[i] = i1; gapA[i] = v1 - v2;
}

// K4: sort approx values, find rank-2048 value vb, mark+compact rescue rows.
__global__ __launch_bounds__(1024) void k_mark(const float* __restrict__ valA,
                                               const float* __restrict__ gapA,
                                               int* __restrict__ rescueCnt,
                                               int* __restrict__ rescueIdx) {
  __shared__ unsigned long long keys[NA];
  __shared__ float vbS;
  const int b = blockIdx.x, t = threadIdx.x;
  for (int p = t; p < NA; p += 1024) {
    float v = valA[(size_t)b * NA + p];
    unsigned u = __float_as_uint(v);
    unsigned mono = u ^ ((u >> 31) ? 0xFFFFFFFFu : 0x80000000u);
    keys[p] = ((unsigned long long)(~mono) << 32) | (unsigned)p;
  }
  __syncthreads();
  for (int k = 2; k <= NA; k <<= 1) {
    for (int j = k >> 1; j > 0; j >>= 1) {
      for (int p = t; p < NA; p += 1024) {
        int q = p ^ j;
        if (q > p) {
          bool up = ((p & k) == 0);
          unsigned long long a = keys[p], c = keys[q];
          if ((a > c) == up) { keys[p] = c; keys[q] = a; }
        }
      }
      __syncthreads();
    }
  }
  if (t == 0) {
    unsigned mono = ~(unsigned)(keys[RSEL - 1] >> 32);
    unsigned u = (mono >> 31) ? (mono ^ 0x80000000u) : ~mono;
    vbS = __uint_as_float(u);
  }
  __syncthreads();
  float vb = vbS;
  for (int p = t; p < NA; p += 1024) {
    size_t o = (size_t)b * NA + p;
    if (gapA[o] < GAP_DELTA || fabsf(valA[o] - vb) <= WIN_TAU) {
      int slot = atomicAdd(&rescueCnt[b], 1);
      if (slot < RESCUE_CAP) rescueIdx[b * RESCUE_CAP + slot] = p;
    }
  }
}

// K5: exact fp32 recompute, parallel over (slot x 16 column-chunks).
// Each thread owns ONE column (full-K dot, independent 64B-line loads);
// block reduces (v desc, c asc) and atomicMax's a packed u64 key.
__global__ __launch_bounds__(256) void k_rescue(const float* __restrict__ ma,
                                                const float* __restrict__ mb,
                                                const int* __restrict__ rescueIdx,
                                                const int* __restrict__ rescueCnt,
                                                unsigned long long* __restrict__ key) {
  const int bq = blockIdx.x >> 8;          // grid = BQ*256
  const int wid = blockIdx.x & 255;
  const int cnt = min(rescueCnt[bq], RESCUE_CAP);
  const int npair = cnt * 16;
  const int t = threadIdx.x;
  __shared__ float sA[128];
  __shared__ float wv[4];
  __shared__ int   wi[4];
  for (int pair = wid; pair < npair; pair += 256) {
    const int slot = pair >> 4, chunk = pair & 15;
    const int row = rescueIdx[bq * RESCUE_CAP + slot];
    __syncthreads();                       // protect sA/wv/wi reuse
    if (t < 128) sA[t] = ma[((size_t)bq * NA + row) * MDIM + t];
    __syncthreads();
    const int c = chunk * 256 + t;
    const float* bp = mb + ((size_t)bq * NA + c) * MDIM;
    float d0 = 0.f, d1 = 0.f, d2 = 0.f, d3 = 0.f;
#pragma unroll
    for (int j = 0; j < 8; ++j) {
      float4 b0 = *(const float4*)(bp + j * 16 + 0);
      float4 b1 = *(const float4*)(bp + j * 16 + 4);
      float4 b2 = *(const float4*)(bp + j * 16 + 8);
      float4 b3 = *(const float4*)(bp + j * 16 + 12);
      const float4 a0 = *(const float4*)&sA[j * 16 + 0];
      const float4 a1 = *(const float4*)&sA[j * 16 + 4];
      const float4 a2 = *(const float4*)&sA[j * 16 + 8];
      const float4 a3 = *(const float4*)&sA[j * 16 + 12];
      d0 = fmaf(a0.x, b0.x, d0); d0 = fmaf(a0.y, b0.y, d0);
      d0 = fmaf(a0.z, b0.z, d0); d0 = fmaf(a0.w, b0.w, d0);
      d1 = fmaf(a1.x, b1.x, d1); d1 = fmaf(a1.y, b1.y, d1);
      d1 = fmaf(a1.z, b1.z, d1); d1 = fmaf(a1.w, b1.w, d1);
      d2 = fmaf(a2.x, b2.x, d2); d2 = fmaf(a2.y, b2.y, d2);
      d2 = fmaf(a2.z, b2.z, d2); d2 = fmaf(a2.w, b2.w, d2);
      d3 = fmaf(a3.x, b3.x, d3); d3 = fmaf(a3.y, b3.y, d3);
      d3 = fmaf(a3.z, b3.z, d3); d3 = fmaf(a3.w, b3.w, d3);
    }
    float d = (d0 + d1) + (d2 + d3);
    int ci = c;
#pragma unroll
    for (int m = 1; m < 64; m <<= 1) {
      float V = __shfl_xor(d, m);
      int C = __shfl_xor(ci, m);
      if (V > d || (V == d && C < ci)) { d = V; ci = C; }
    }
    if ((t & 63) == 0) { wv[t >> 6] = d; wi[t >> 6] = ci; }
    __syncthreads();
    if (t == 0) {
      for (int w2 = 1; w2 < 4; ++w2)
        if (wv[w2] > d || (wv[w2] == d && wi[w2] < ci)) { d = wv[w2]; ci = wi[w2]; }
      unsigned u = __float_as_uint(d);
      unsigned mono = u ^ ((u >> 31) ? 0xFFFFFFFFu : 0x80000000u);
      unsigned long long k = ((unsigned long long)mono << 32)
                           | (unsigned)(0xFFFFFFFFu - (unsigned)ci);
      atomicMax(&key[(size_t)bq * NA + row], k);
    }
  }
}

// K5b: decode packed keys for rescued rows into valA/nodeA
__global__ void k_finalize(const unsigned long long* __restrict__ key,
                           float* __restrict__ valA, int* __restrict__ nodeA) {
  int i = blockIdx.x * 256 + threadIdx.x;
  if (i >= BQ * NA) return;
  unsigned long long k = key[i];
  if (k) {
    unsigned mono = (unsigned)(k >> 32);
    unsigned u = (mono & 0x80000000u) ? (mono ^ 0x80000000u) : ~mono;
    valA[i] = __uint_as_float(u);
    nodeA[i] = (int)(0xFFFFFFFFu - (unsigned)(k & 0xFFFFFFFFull));
  }
}

// K6: exact top-2048 of final values (bitonic, replicates top_k partition)
__global__ __launch_bounds__(1024) void k_topk(const float* __restrict__ values,
                                               int* __restrict__ sel) {
  __shared__ unsigned long long keys[NA];
  const int b = blockIdx.x, t = threadIdx.x;
  for (int p = t; p < NA; p += 1024) {
    float v = values[(size_t)b * NA + p];
    unsigned u = __float_as_uint(v);
    unsigned mono = u ^ ((u >> 31) ? 0xFFFFFFFFu : 0x80000000u);
    keys[p] = ((unsigned long long)(~mono) << 32) | (unsigned)p;
  }
  __syncthreads();
  for (int k = 2; k <= NA; k <<= 1) {
    for (int j = k >> 1; j > 0; j >>= 1) {
      for (int p = t; p < NA; p += 1024) {
        int q = p ^ j;
        if (q > p) {
          bool up = ((p & k) == 0);
          unsigned long long a = keys[p], c = keys[q];
          if ((a > c) == up) { keys[p] = c; keys[q] = a; }
        }
      }
      __syncthreads();
    }
  }
  for (int p = t; p < NA; p += 1024) {
    int idx = (int)(keys[p] & 0xFFFFFFFFull);
    sel[(size_t)b * NA + idx] = (p < RSEL) ? 1 : 0;
  }
}

// K7: per-destination merge lists (count + atomicExch linked list)
__global__ void k_build(const int* __restrict__ sel, const int* __restrict__ node,
                        int* __restrict__ cnt, int* __restrict__ head,
                        int* __restrict__ nxt) {
  int i = blockIdx.x * 256 + threadIdx.x;
  if (i >= BQ * NA) return;
  int bq = i >> 12, k = i & (NA - 1);
  if (sel[i]) {
    int dst = node[i];
    atomicAdd(&cnt[(size_t)bq * NA + dst], 1);
    nxt[i] = atomicExch(&head[(size_t)bq * NA + dst], k);
  }
}

// K8: mask scan -> new_idx; ownership output (float32). One block per batch.
__global__ __launch_bounds__(1024) void k_scan(const int* __restrict__ sel,
                                               const int* __restrict__ node,
                                               int* __restrict__ newidx,
                                               float* __restrict__ own) {
  __shared__ int ni[NTOK];
  __shared__ int tot[1024];
  const int b = blockIdx.x, t = threadIdx.x;
  const int base = t * 8;
  int kept[8], run = 0;
#pragma unroll
  for (int e = 0; e < 8; ++e) {
    int idx = base + e;
    int kp = ((idx & 1) == 0) ? 1 : (sel[(size_t)b * NA + (idx >> 1)] ? 0 : 1);
    kept[e] = kp;
    run += kp;
  }
  tot[t] = run;
  __syncthreads();
  for (int off = 1; off < 1024; off <<= 1) {
    int v = (t >= off) ? tot[t - off] : 0;
    __syncthreads();
    tot[t] += v;
    __syncthreads();
  }
  int cum = tot[t] - run;
#pragma unroll
  for (int e = 0; e < 8; ++e) {
    cum += kept[e];
    ni[base + e] = cum - 1;
  }
  __syncthreads();
#pragma unroll
  for (int e = 0; e < 8; ++e) {
    int idx = base + e;
    int ow = kept[e] ? ni[idx] : ni[2 * node[(size_t)b * NA + (idx >> 1)]];
    newidx[(size_t)b * NTOK + idx] = ni[idx];
    own[(size_t)b * NTOK + idx] = (float)ow;
  }
}

// K9: assemble x_final f32 (gather merges via linked list, divide, compact)
__global__ __launch_bounds__(128) void k_assemble(const float* __restrict__ X,
                                                  const int* __restrict__ sel,
                                                  const int* __restrict__ newidx,
                                                  const int* __restrict__ cnt,
                                                  const int* __restrict__ head,
                                                  const int* __restrict__ nxt,
                                                  float* __restrict__ out) {
  const int token = blockIdx.x;
  const int bq = token >> 13, tp = token & (NTOK - 1);
  if ((tp & 1) && sel[(size_t)bq * NA + (tp >> 1)]) return;
  const int t = threadIdx.x;
  float4 v = *(const float4*)(X + (size_t)token * CDIM + t * 4);
  if (!(tp & 1)) {
    size_t slot = (size_t)bq * NA + (tp >> 1);
    int c = cnt[slot];
    if (c > 0) {
      int kk = head[slot];
      while (kk >= 0) {
        float4 s = *(const float4*)(X + ((size_t)bq * NTOK + 2 * kk + 1) * CDIM + t * 4);
        v.x += s.x; v.y += s.y; v.z += s.z; v.w += s.w;
        kk = nxt[(size_t)bq * NA + kk];
      }
      float inv = 1.0f / (float)(1 + c);
      v.x *= inv; v.y *= inv; v.z *= inv; v.w *= inv;
    }
  }
  int dst = newidx[(size_t)bq * NTOK + tp];
  *(float4*)(out + ((size_t)bq * NKEEP + dst) * CDIM + t * 4) = v;
}

// ---------------------------------------------------------------------------
extern "C" void kernel_launch(void* const* d_in, const int* in_sizes, int n_in,
                              void* d_out, int out_size, void* d_ws, size_t ws_size,
                              hipStream_t stream) {
  const float* X    = (const float*)d_in[0];
  const float* W    = (const float*)d_in[1];
  const float* bias = (const float*)d_in[2];
  float* out = (float*)d_out;  // f32: x_final (4,6144,512) ++ ownership (4,8192)
  char* ws = (char*)d_ws;

  size_t o = 0;
  float* ma   = (float*)(ws + o); o += (size_t)BQ * NA * MDIM * 4;   // 8 MB
  float* mb   = (float*)(ws + o); o += (size_t)BQ * NA * MDIM * 4;   // 8 MB
  unsigned short* maH = (unsigned short*)(ws + o); o += (size_t)BQ * NA * MDIM * 2;
  unsigned short* maM = (unsigned short*)(ws + o); o += (size_t)BQ * NA * MDIM * 2;
  unsigned short* mbH = (unsigned short*)(ws + o); o += (size_t)BQ * NA * MDIM * 2;
  unsigned short* mbM = (unsigned short*)(ws + o); o += (size_t)BQ * NA * MDIM * 2;
  float* pv1  = (float*)(ws + o); o += (size_t)BQ * 4 * NA * 4;
  int*   pi1  = (int*)(ws + o);   o += (size_t)BQ * 4 * NA * 4;
  float* pv2  = (float*)(ws + o); o += (size_t)BQ * 4 * NA * 4;
  float* valA = (float*)(ws + o); o += (size_t)BQ * NA * 4;
  int*   nodeA= (int*)(ws + o);   o += (size_t)BQ * NA * 4;
  float* gapA = (float*)(ws + o); o += (size_t)BQ * NA * 4;
  int*   sel  = (int*)(ws + o);   o += (size_t)BQ * NA * 4;
  int*   cnt  = (int*)(ws + o);   o += (size_t)BQ * NA * 4;
  int*   head = (int*)(ws + o);   o += (size_t)BQ * NA * 4;
  int*   nxt  = (int*)(ws + o);   o += (size_t)BQ * NA * 4;
  int*   newidx = (int*)(ws + o); o += (size_t)BQ * NTOK * 4;
  int*   rescueCnt = (int*)(ws + o); o += 256;
  int*   rescueIdx = (int*)(ws + o); o += (size_t)BQ * RESCUE_CAP * 4;
  unsigned long long* rescueKey = (unsigned long long*)(ws + o); o += (size_t)BQ * NA * 8;
  (void)in_sizes; (void)n_in; (void)out_size; (void)ws_size;

  hipMemsetAsync(cnt, 0, (size_t)BQ * NA * 4, stream);
  hipMemsetAsync(head, 0xFF, (size_t)BQ * NA * 4, stream);
  hipMemsetAsync(rescueCnt, 0, 256, stream);
  hipMemsetAsync(rescueKey, 0, (size_t)BQ * NA * 8, stream);

  k_metric<<<512, 256, 0, stream>>>(X, W, bias, ma, mb, maH, maM, mbH, mbM);
  k_scores_mfma<<<512, 256, 0, stream>>>(maH, maM, mbH, mbM, pv1, pi1, pv2);
  k_merge4<<<(BQ * NA + 255) / 256, 256, 0, stream>>>(pv1, pi1, pv2, valA, nodeA, gapA);
  k_mark<<<BQ, 1024, 0, stream>>>(valA, gapA, rescueCnt, rescueIdx);
  k_rescue<<<BQ * 256, 256, 0, stream>>>(ma, mb, rescueIdx, rescueCnt, rescueKey);
  k_finalize<<<(BQ * NA + 255) / 256, 256, 0, stream>>>(rescueKey, valA, nodeA);
  k_topk<<<BQ, 1024, 0, stream>>>(valA, sel);
  k_build<<<(BQ * NA + 255) / 256, 256, 0, stream>>>(sel, nodeA, cnt, head, nxt);
  k_scan<<<BQ, 1024, 0, stream>>>(sel, nodeA, newidx, out + (size_t)BQ * NKEEP * CDIM);
  k_assemble<<<BQ * NTOK, 128, 0, stream>>>(X, sel, newidx, cnt, head, nxt, out);
}

// Round 6
// 380.360 us; speedup vs baseline: 1.6056x; 1.0876x over previous
//
#include <hip/hip_runtime.h>
#include <cstdint>
#include <cstddef>

#define BQ    4
#define NTOK  8192
#define CDIM  512
#define MDIM  128
#define NA    4096
#define RSEL  2048
#define NKEEP (NTOK - RSEL)   // 6144
#define RESCUE_CAP 2048
#define GAP_DELTA 2e-4f
#define WIN_TAU   2e-4f
#define CSPL  8

typedef float f32x4 __attribute__((ext_vector_type(4)));
typedef short short8 __attribute__((ext_vector_type(8)));

static __device__ __forceinline__ unsigned short bf16rne(float f) {
  unsigned u = __float_as_uint(f);
  return (unsigned short)((u + 0x7FFFu + ((u >> 16) & 1)) >> 16);
}

// ---------------------------------------------------------------------------
// K1: metric = x @ W^T + b, row-normalize, split even/odd rows into ma/mb
// (fp32) AND emit bf16 hi/mid planes. 512 blocks x 64-token tiles, K-chunk 64.
// ---------------------------------------------------------------------------
__global__ __launch_bounds__(256) void k_metric(const float* __restrict__ X,
                                                const float* __restrict__ W,
                                                const float* __restrict__ bias,
                                                float* __restrict__ ma,
                                                float* __restrict__ mb,
                                                unsigned short* __restrict__ maH,
                                                unsigned short* __restrict__ maM,
                                                unsigned short* __restrict__ mbH,
                                                unsigned short* __restrict__ mbM) {
  __shared__ float ldsA[64 * 64];
  __shared__ float ldsB[128 * 64];
  __shared__ float snorm[64 * 16];
  __shared__ float sinv[64];
  const int t = threadIdx.x;
  const int tok0 = blockIdx.x * 64;
  const int r16 = t & 15, g = t >> 4;

  float acc[4][8];
#pragma unroll
  for (int i = 0; i < 4; ++i)
#pragma unroll
    for (int j = 0; j < 8; ++j) acc[i][j] = 0.f;

  for (int kc = 0; kc < 8; ++kc) {
    __syncthreads();
#pragma unroll
    for (int it = 0; it < 4; ++it) {
      int f = it * 256 + t;
      int row = f >> 4, k4 = f & 15;
      float4 xv = *(const float4*)(X + (size_t)(tok0 + row) * CDIM + kc * 64 + k4 * 4);
      *(float4*)&ldsA[row * 64 + ((k4 ^ (row & 15)) << 2)] = xv;
    }
#pragma unroll
    for (int it = 0; it < 8; ++it) {
      int f = it * 256 + t;
      int row = f >> 4, k4 = f & 15;
      float4 wv = *(const float4*)(W + (size_t)row * CDIM + kc * 64 + k4 * 4);
      *(float4*)&ldsB[row * 64 + ((k4 ^ (row & 15)) << 2)] = wv;
    }
    __syncthreads();
#pragma unroll 4
    for (int kq = 0; kq < 16; ++kq) {
      float4 av[4], bv[8];
#pragma unroll
      for (int i = 0; i < 4; ++i) {
        int r = r16 + (i << 4);
        av[i] = *(const float4*)&ldsA[r * 64 + ((kq ^ (r & 15)) << 2)];
      }
#pragma unroll
      for (int j = 0; j < 8; ++j) {
        int cc = (g << 3) + j;
        bv[j] = *(const float4*)&ldsB[cc * 64 + ((kq ^ (cc & 15)) << 2)];
      }
#pragma unroll
      for (int i = 0; i < 4; ++i)
#pragma unroll
        for (int j = 0; j < 8; ++j) {
          acc[i][j] = fmaf(av[i].x, bv[j].x, acc[i][j]);
          acc[i][j] = fmaf(av[i].y, bv[j].y, acc[i][j]);
          acc[i][j] = fmaf(av[i].z, bv[j].z, acc[i][j]);
          acc[i][j] = fmaf(av[i].w, bv[j].w, acc[i][j]);
        }
    }
  }

  float bb[8];
#pragma unroll
  for (int j = 0; j < 8; ++j) bb[j] = bias[(g << 3) + j];
#pragma unroll
  for (int i = 0; i < 4; ++i) {
    float s = 0.f;
#pragma unroll
    for (int j = 0; j < 8; ++j) {
      acc[i][j] += bb[j];
      s = fmaf(acc[i][j], acc[i][j], s);
    }
    snorm[(r16 + (i << 4)) * 16 + g] = s;
  }
  __syncthreads();
  if (t < 64) {
    float s = 0.f;
    for (int q = 0; q < 16; ++q) s += snorm[t * 16 + q];
    sinv[t] = 1.0f / sqrtf(s);
  }
  __syncthreads();
#pragma unroll
  for (int i = 0; i < 4; ++i) {
    int r = r16 + (i << 4);
    int tokg = tok0 + r;
    float inv = sinv[r];
    int bq = tokg >> 13, pos = tokg & (NTOK - 1);
    size_t eidx = ((size_t)bq * NA + (pos >> 1)) * MDIM + (g << 3);
    float vv[8];
#pragma unroll
    for (int j = 0; j < 8; ++j) vv[j] = acc[i][j] * inv;
    float* dst = ((pos & 1) ? mb : ma) + eidx;
    *(float4*)dst = make_float4(vv[0], vv[1], vv[2], vv[3]);
    *(float4*)(dst + 4) = make_float4(vv[4], vv[5], vv[6], vv[7]);
    unsigned hB[8], mB[8];
#pragma unroll
    for (int j = 0; j < 8; ++j) {
      hB[j] = bf16rne(vv[j]);
      mB[j] = bf16rne(vv[j] - __uint_as_float(hB[j] << 16));
    }
    uint4 hw, mw;
    hw.x = hB[0] | (hB[1] << 16); hw.y = hB[2] | (hB[3] << 16);
    hw.z = hB[4] | (hB[5] << 16); hw.w = hB[6] | (hB[7] << 16);
    mw.x = mB[0] | (mB[1] << 16); mw.y = mB[2] | (mB[3] << 16);
    mw.z = mB[4] | (mB[5] << 16); mw.w = mB[6] | (mB[7] << 16);
    *(uint4*)(((pos & 1) ? mbH : maH) + eidx) = hw;
    *(uint4*)(((pos & 1) ? mbM : maM) + eidx) = mw;
  }
}

// ---------------------------------------------------------------------------
// K2: scores via split-bf16 MFMA (hi*hi + hi*mid + mid*hi), per-row top-2.
// Occupancy-first layout: 16 a-rows/wave (64/block), 512-c split, 32-c chunks
// double-buffered in 32 KB LDS. grid = 4 bq x 64 at x 8 cs = 2048 blocks;
// 4 blocks/CU x 4 waves = 16 waves/CU.
// ---------------------------------------------------------------------------
__global__ __launch_bounds__(256, 4) void k_scores_mfma(
    const unsigned short* __restrict__ maH, const unsigned short* __restrict__ maM,
    const unsigned short* __restrict__ mbH, const unsigned short* __restrict__ mbM,
    float* __restrict__ pv1, int* __restrict__ pi1, float* __restrict__ pv2) {
  __shared__ short8 lds8[2][2][32][16];   // [buf][plane][c][k-granule], 32 KB
  const int t = threadIdx.x;
  const int bid = blockIdx.x;
  const int bq = bid >> 9, rem = bid & 511, at = rem >> 3, cs = rem & 7;
  const int a0 = at * 64;
  const int l = t & 63, w = t >> 6;
  const int l15 = l & 15, l4 = l >> 4, l7 = l & 7;

  // A fragments: 16 rows per wave, K=128 in 4 chunks, hi+mid planes (32 VGPR).
  short8 aH[4], aM[4];
#pragma unroll
  for (int kc = 0; kc < 4; ++kc) {
    size_t aidx = ((size_t)bq * NA + a0 + w * 16 + l15) * MDIM + kc * 32 + l4 * 8;
    aH[kc] = *(const short8*)(maH + aidx);
    aM[kc] = *(const short8*)(maM + aidx);
  }

  // staging: waves 0-1 stage hi plane, 2-3 stage mid; 4 x 1KB loads per wave
  // per chunk. Source pre-swizzled (granule ^= c&7); LDS dest linear.
  const unsigned short* bplane = (w >> 1) ? mbM : mbH;
  const char* sp0; const char* sp1; const char* sp2; const char* sp3;
  {
    const int clb = (w & 1) * 16 + l4;
    const size_t rowb = (size_t)bq * NA + cs * 512;
    sp0 = (const char*)bplane + ((rowb + clb +  0) << 8) + ((l15 ^ ((clb +  0) & 7)) << 4);
    sp1 = (const char*)bplane + ((rowb + clb +  4) << 8) + ((l15 ^ ((clb +  4) & 7)) << 4);
    sp2 = (const char*)bplane + ((rowb + clb +  8) << 8) + ((l15 ^ ((clb +  8) & 7)) << 4);
    sp3 = (const char*)bplane + ((rowb + clb + 12) << 8) + ((l15 ^ ((clb + 12) & 7)) << 4);
  }

  float bv1[4], bv2[4];
  int bi1[4];
#pragma unroll
  for (int s = 0; s < 4; ++s) { bv1[s] = -1e30f; bv2[s] = -1e30f; bi1[s] = 0x7FFFFFFF; }

  auto stage = [&](int bufn) {
    char* dst = (char*)&lds8[bufn][0][0][0] + w * 4096 + l * 16;
    __builtin_amdgcn_global_load_lds((const __attribute__((address_space(1))) void*)sp0,
        (__attribute__((address_space(3))) void*)(dst + 0),    16, 0, 0);
    __builtin_amdgcn_global_load_lds((const __attribute__((address_space(1))) void*)sp1,
        (__attribute__((address_space(3))) void*)(dst + 1024), 16, 0, 0);
    __builtin_amdgcn_global_load_lds((const __attribute__((address_space(1))) void*)sp2,
        (__attribute__((address_space(3))) void*)(dst + 2048), 16, 0, 0);
    __builtin_amdgcn_global_load_lds((const __attribute__((address_space(1))) void*)sp3,
        (__attribute__((address_space(3))) void*)(dst + 3072), 16, 0, 0);
    sp0 += 8192; sp1 += 8192; sp2 += 8192; sp3 += 8192;
  };

  auto compute = [&](int bufn, int cbase) {
    f32x4 acc1[2], acc2[2];
    acc1[0] = 0.f; acc1[1] = 0.f; acc2[0] = 0.f; acc2[1] = 0.f;
#pragma unroll
    for (int kc = 0; kc < 4; ++kc) {
      const int gg = (kc * 4 + l4) ^ l7;
#pragma unroll
      for (int cf = 0; cf < 2; ++cf) {
        short8 bh = lds8[bufn][0][cf * 16 + l15][gg];
        short8 bm = lds8[bufn][1][cf * 16 + l15][gg];
        acc1[cf] = __builtin_amdgcn_mfma_f32_16x16x32_bf16(aH[kc], bh, acc1[cf], 0, 0, 0);
        acc2[cf] = __builtin_amdgcn_mfma_f32_16x16x32_bf16(aH[kc], bm, acc2[cf], 0, 0, 0);
        acc2[cf] = __builtin_amdgcn_mfma_f32_16x16x32_bf16(aM[kc], bh, acc2[cf], 0, 0, 0);
      }
    }
#pragma unroll
    for (int cf = 0; cf < 2; ++cf) {
      const int cg = cbase + cf * 16 + l15;
      f32x4 v4 = acc1[cf] + acc2[cf];
#pragma unroll
      for (int r2 = 0; r2 < 4; ++r2) {
        float v = v4[r2];
        if (v > bv1[r2]) { bv2[r2] = bv1[r2]; bv1[r2] = v; bi1[r2] = cg; }
        else if (v > bv2[r2]) bv2[r2] = v;
      }
    }
  };

  stage(0);
  __syncthreads();
  const int cb0 = cs * 512;
  for (int chp = 0; chp < 8; ++chp) {   // 16 chunks of 32 c, 2 per iteration
    const int ch = chp * 2;
    if (ch + 1 < 16) stage(1);
    compute(0, cb0 + ch * 32);
    __syncthreads();
    if (ch + 2 < 16) stage(0);
    compute(1, cb0 + ch * 32 + 32);
    __syncthreads();
  }

  // cross-lane top-2 reduce over the 16 col-lanes sharing each row
#pragma unroll
  for (int s = 0; s < 4; ++s) {
    float v1 = bv1[s], v2 = bv2[s];
    int i1 = bi1[s];
#pragma unroll
    for (int m = 1; m < 16; m <<= 1) {
      float V1 = __shfl_xor(v1, m);
      int I1 = __shfl_xor(i1, m);
      float V2 = __shfl_xor(v2, m);
      bool take = (V1 > v1) || (V1 == v1 && I1 < i1);
      float lose = take ? v1 : V1;
      if (take) { v1 = V1; i1 = I1; }
      v2 = fmaxf(fmaxf(v2, V2), lose);
    }
    if (l15 == s) {
      int row = a0 + w * 16 + l4 * 4 + s;
      size_t off = ((size_t)(bq * CSPL + cs)) * NA + row;
      pv1[off] = v1; pi1[off] = i1; pv2[off] = v2;
    }
  }
}

// K3: merge the 8 csplit partials -> value, node, gap
__global__ void k_merge8(const float* __restrict__ pv1, const int* __restrict__ pi1,
                         const float* __restrict__ pv2,
                         float* __restrict__ valA, int* __restrict__ nodeA,
                         float* __restrict__ gapA) {
  int i = blockIdx.x * 256 + threadIdx.x;
  if (i >= BQ * NA) return;
  int bq = i >> 12, row = i & (NA - 1);
  float v1 = -1e30f, v2 = -1e30f;
  int i1 = 0x7FFFFFFF;
#pragma unroll
  for (int cspl = 0; cspl < CSPL; ++cspl) {
    size_t o = ((size_t)(bq * CSPL + cspl)) * NA + row;
    float V1 = pv1[o], V2 = pv2[o];
    int I1 = pi1[o];
    bool take = (V1 > v1) || (V1 == v1 && I1 < i1);
    float lose = take ? v1 : V1;
    if (take) { v1 = V1; i1 = I1; }
    v2 = fmaxf(fmaxf(v2, V2), lose);
  }
  valA[i] = v1; nodeA[i] = i1; gapA[i] = v1 - v2;
}

// K4: sort approx values, find rank-2048 value vb, mark+compact rescue rows.
__global__ __launch_bounds__(1024) void k_mark(const float* __restrict__ valA,
                                               const float* __restrict__ gapA,
                                               int* __restrict__ rescueCnt,
                                               int* __restrict__ rescueIdx) {
  __shared__ unsigned long long keys[NA];
  __shared__ float vbS;
  const int b = blockIdx.x, t = threadIdx.x;
  for (int p = t; p < NA; p += 1024) {
    float v = valA[(size_t)b * NA + p];
    unsigned u = __float_as_uint(v);
    unsigned mono = u ^ ((u >> 31) ? 0xFFFFFFFFu : 0x80000000u);
    keys[p] = ((unsigned long long)(~mono) << 32) | (unsigned)p;
  }
  __syncthreads();
  for (int k = 2; k <= NA; k <<= 1) {
    for (int j = k >> 1; j > 0; j >>= 1) {
      for (int p = t; p < NA; p += 1024) {
        int q = p ^ j;
        if (q > p) {
          bool up = ((p & k) == 0);
          unsigned long long a = keys[p], c = keys[q];
          if ((a > c) == up) { keys[p] = c; keys[q] = a; }
        }
      }
      __syncthreads();
    }
  }
  if (t == 0) {
    unsigned mono = ~(unsigned)(keys[RSEL - 1] >> 32);
    unsigned u = (mono >> 31) ? (mono ^ 0x80000000u) : ~mono;
    vbS = __uint_as_float(u);
  }
  __syncthreads();
  float vb = vbS;
  for (int p = t; p < NA; p += 1024) {
    size_t o = (size_t)b * NA + p;
    if (gapA[o] < GAP_DELTA || fabsf(valA[o] - vb) <= WIN_TAU) {
      int slot = atomicAdd(&rescueCnt[b], 1);
      if (slot < RESCUE_CAP) rescueIdx[b * RESCUE_CAP + slot] = p;
    }
  }
}

// K5: exact fp32 recompute, parallel over (slot x 16 column-chunks).
__global__ __launch_bounds__(256) void k_rescue(const float* __restrict__ ma,
                                                const float* __restrict__ mb,
                                                const int* __restrict__ rescueIdx,
                                                const int* __restrict__ rescueCnt,
                                                unsigned long long* __restrict__ key) {
  const int bq = blockIdx.x >> 8;
  const int wid = blockIdx.x & 255;
  const int cnt = min(rescueCnt[bq], RESCUE_CAP);
  const int npair = cnt * 16;
  const int t = threadIdx.x;
  __shared__ float sA[128];
  __shared__ float wv[4];
  __shared__ int   wi[4];
  for (int pair = wid; pair < npair; pair += 256) {
    const int slot = pair >> 4, chunk = pair & 15;
    const int row = rescueIdx[bq * RESCUE_CAP + slot];
    __syncthreads();
    if (t < 128) sA[t] = ma[((size_t)bq * NA + row) * MDIM + t];
    __syncthreads();
    const int c = chunk * 256 + t;
    const float* bp = mb + ((size_t)bq * NA + c) * MDIM;
    float d0 = 0.f, d1 = 0.f, d2 = 0.f, d3 = 0.f;
#pragma unroll
    for (int j = 0; j < 8; ++j) {
      float4 b0 = *(const float4*)(bp + j * 16 + 0);
      float4 b1 = *(const float4*)(bp + j * 16 + 4);
      float4 b2 = *(const float4*)(bp + j * 16 + 8);
      float4 b3 = *(const float4*)(bp + j * 16 + 12);
      const float4 a0 = *(const float4*)&sA[j * 16 + 0];
      const float4 a1 = *(const float4*)&sA[j * 16 + 4];
      const float4 a2 = *(const float4*)&sA[j * 16 + 8];
      const float4 a3 = *(const float4*)&sA[j * 16 + 12];
      d0 = fmaf(a0.x, b0.x, d0); d0 = fmaf(a0.y, b0.y, d0);
      d0 = fmaf(a0.z, b0.z, d0); d0 = fmaf(a0.w, b0.w, d0);
      d1 = fmaf(a1.x, b1.x, d1); d1 = fmaf(a1.y, b1.y, d1);
      d1 = fmaf(a1.z, b1.z, d1); d1 = fmaf(a1.w, b1.w, d1);
      d2 = fmaf(a2.x, b2.x, d2); d2 = fmaf(a2.y, b2.y, d2);
      d2 = fmaf(a2.z, b2.z, d2); d2 = fmaf(a2.w, b2.w, d2);
      d3 = fmaf(a3.x, b3.x, d3); d3 = fmaf(a3.y, b3.y, d3);
      d3 = fmaf(a3.z, b3.z, d3); d3 = fmaf(a3.w, b3.w, d3);
    }
    float d = (d0 + d1) + (d2 + d3);
    int ci = c;
#pragma unroll
    for (int m = 1; m < 64; m <<= 1) {
      float V = __shfl_xor(d, m);
      int C = __shfl_xor(ci, m);
      if (V > d || (V == d && C < ci)) { d = V; ci = C; }
    }
    if ((t & 63) == 0) { wv[t >> 6] = d; wi[t >> 6] = ci; }
    __syncthreads();
    if (t == 0) {
      for (int w2 = 1; w2 < 4; ++w2)
        if (wv[w2] > d || (wv[w2] == d && wi[w2] < ci)) { d = wv[w2]; ci = wi[w2]; }
      unsigned u = __float_as_uint(d);
      unsigned mono = u ^ ((u >> 31) ? 0xFFFFFFFFu : 0x80000000u);
      unsigned long long k = ((unsigned long long)mono << 32)
                           | (unsigned)(0xFFFFFFFFu - (unsigned)ci);
      atomicMax(&key[(size_t)bq * NA + row], k);
    }
  }
}

// K5b: decode packed keys for rescued rows into valA/nodeA
__global__ void k_finalize(const unsigned long long* __restrict__ key,
                           float* __restrict__ valA, int* __restrict__ nodeA) {
  int i = blockIdx.x * 256 + threadIdx.x;
  if (i >= BQ * NA) return;
  unsigned long long k = key[i];
  if (k) {
    unsigned mono = (unsigned)(k >> 32);
    unsigned u = (mono & 0x80000000u) ? (mono ^ 0x80000000u) : ~mono;
    valA[i] = __uint_as_float(u);
    nodeA[i] = (int)(0xFFFFFFFFu - (unsigned)(k & 0xFFFFFFFFull));
  }
}

// K6: exact top-2048 of final values (bitonic, replicates top_k partition)
__global__ __launch_bounds__(1024) void k_topk(const float* __restrict__ values,
                                               int* __restrict__ sel) {
  __shared__ unsigned long long keys[NA];
  const int b = blockIdx.x, t = threadIdx.x;
  for (int p = t; p < NA; p += 1024) {
    float v = values[(size_t)b * NA + p];
    unsigned u = __float_as_uint(v);
    unsigned mono = u ^ ((u >> 31) ? 0xFFFFFFFFu : 0x80000000u);
    keys[p] = ((unsigned long long)(~mono) << 32) | (unsigned)p;
  }
  __syncthreads();
  for (int k = 2; k <= NA; k <<= 1) {
    for (int j = k >> 1; j > 0; j >>= 1) {
      for (int p = t; p < NA; p += 1024) {
        int q = p ^ j;
        if (q > p) {
          bool up = ((p & k) == 0);
          unsigned long long a = keys[p], c = keys[q];
          if ((a > c) == up) { keys[p] = c; keys[q] = a; }
        }
      }
      __syncthreads();
    }
  }
  for (int p = t; p < NA; p += 1024) {
    int idx = (int)(keys[p] & 0xFFFFFFFFull);
    sel[(size_t)b * NA + idx] = (p < RSEL) ? 1 : 0;
  }
}

// K7: per-destination merge lists (count + atomicExch linked list)
__global__ void k_build(const int* __restrict__ sel, const int* __restrict__ node,
                        int* __restrict__ cnt, int* __restrict__ head,
                        int* __restrict__ nxt) {
  int i = blockIdx.x * 256 + threadIdx.x;
  if (i >= BQ * NA) return;
  int bq = i >> 12, k = i & (NA - 1);
  if (sel[i]) {
    int dst = node[i];
    atomicAdd(&cnt[(size_t)bq * NA + dst], 1);
    nxt[i] = atomicExch(&head[(size_t)bq * NA + dst], k);
  }
}

// K8: mask scan -> new_idx; ownership output (float32). One block per batch.
__global__ __launch_bounds__(1024) void k_scan(const int* __restrict__ sel,
                                               const int* __restrict__ node,
                                               int* __restrict__ newidx,
                                               float* __restrict__ own) {
  __shared__ int ni[NTOK];
  __shared__ int tot[1024];
  const int b = blockIdx.x, t = threadIdx.x;
  const int base = t * 8;
  int kept[8], run = 0;
#pragma unroll
  for (int e = 0; e < 8; ++e) {
    int idx = base + e;
    int kp = ((idx & 1) == 0) ? 1 : (sel[(size_t)b * NA + (idx >> 1)] ? 0 : 1);
    kept[e] = kp;
    run += kp;
  }
  tot[t] = run;
  __syncthreads();
  for (int off = 1; off < 1024; off <<= 1) {
    int v = (t >= off) ? tot[t - off] : 0;
    __syncthreads();
    tot[t] += v;
    __syncthreads();
  }
  int cum = tot[t] - run;
#pragma unroll
  for (int e = 0; e < 8; ++e) {
    cum += kept[e];
    ni[base + e] = cum - 1;
  }
  __syncthreads();
#pragma unroll
  for (int e = 0; e < 8; ++e) {
    int idx = base + e;
    int ow = kept[e] ? ni[idx] : ni[2 * node[(size_t)b * NA + (idx >> 1)]];
    newidx[(size_t)b * NTOK + idx] = ni[idx];
    own[(size_t)b * NTOK + idx] = (float)ow;
  }
}

// K9: assemble x_final f32 (gather merges via linked list, divide, compact)
__global__ __launch_bounds__(128) void k_assemble(const float* __restrict__ X,
                                                  const int* __restrict__ sel,
                                                  const int* __restrict__ newidx,
                                                  const int* __restrict__ cnt,
                                                  const int* __restrict__ head,
                                                  const int* __restrict__ nxt,
                                                  float* __restrict__ out) {
  const int token = blockIdx.x;
  const int bq = token >> 13, tp = token & (NTOK - 1);
  if ((tp & 1) && sel[(size_t)bq * NA + (tp >> 1)]) return;
  const int t = threadIdx.x;
  float4 v = *(const float4*)(X + (size_t)token * CDIM + t * 4);
  if (!(tp & 1)) {
    size_t slot = (size_t)bq * NA + (tp >> 1);
    int c = cnt[slot];
    if (c > 0) {
      int kk = head[slot];
      while (kk >= 0) {
        float4 s = *(const float4*)(X + ((size_t)bq * NTOK + 2 * kk + 1) * CDIM + t * 4);
        v.x += s.x; v.y += s.y; v.z += s.z; v.w += s.w;
        kk = nxt[(size_t)bq * NA + kk];
      }
      float inv = 1.0f / (float)(1 + c);
      v.x *= inv; v.y *= inv; v.z *= inv; v.w *= inv;
    }
  }
  int dst = newidx[(size_t)bq * NTOK + tp];
  *(float4*)(out + ((size_t)bq * NKEEP + dst) * CDIM + t * 4) = v;
}

// ---------------------------------------------------------------------------
extern "C" void kernel_launch(void* const* d_in, const int* in_sizes, int n_in,
                              void* d_out, int out_size, void* d_ws, size_t ws_size,
                              hipStream_t stream) {
  const float* X    = (const float*)d_in[0];
  const float* W    = (const float*)d_in[1];
  const float* bias = (const float*)d_in[2];
  float* out = (float*)d_out;  // f32: x_final (4,6144,512) ++ ownership (4,8192)
  char* ws = (char*)d_ws;

  size_t o = 0;
  float* ma   = (float*)(ws + o); o += (size_t)BQ * NA * MDIM * 4;
  float* mb   = (float*)(ws + o); o += (size_t)BQ * NA * MDIM * 4;
  unsigned short* maH = (unsigned short*)(ws + o); o += (size_t)BQ * NA * MDIM * 2;
  unsigned short* maM = (unsigned short*)(ws + o); o += (size_t)BQ * NA * MDIM * 2;
  unsigned short* mbH = (unsigned short*)(ws + o); o += (size_t)BQ * NA * MDIM * 2;
  unsigned short* mbM = (unsigned short*)(ws + o); o += (size_t)BQ * NA * MDIM * 2;
  float* pv1  = (float*)(ws + o); o += (size_t)BQ * CSPL * NA * 4;
  int*   pi1  = (int*)(ws + o);   o += (size_t)BQ * CSPL * NA * 4;
  float* pv2  = (float*)(ws + o); o += (size_t)BQ * CSPL * NA * 4;
  float* valA = (float*)(ws + o); o += (size_t)BQ * NA * 4;
  int*   nodeA= (int*)(ws + o);   o += (size_t)BQ * NA * 4;
  float* gapA = (float*)(ws + o); o += (size_t)BQ * NA * 4;
  int*   sel  = (int*)(ws + o);   o += (size_t)BQ * NA * 4;
  int*   cnt  = (int*)(ws + o);   o += (size_t)BQ * NA * 4;
  int*   head = (int*)(ws + o);   o += (size_t)BQ * NA * 4;
  int*   nxt  = (int*)(ws + o);   o += (size_t)BQ * NA * 4;
  int*   newidx = (int*)(ws + o); o += (size_t)BQ * NTOK * 4;
  int*   rescueCnt = (int*)(ws + o); o += 256;
  int*   rescueIdx = (int*)(ws + o); o += (size_t)BQ * RESCUE_CAP * 4;
  unsigned long long* rescueKey = (unsigned long long*)(ws + o); o += (size_t)BQ * NA * 8;
  (void)in_sizes; (void)n_in; (void)out_size; (void)ws_size;

  hipMemsetAsync(cnt, 0, (size_t)BQ * NA * 4, stream);
  hipMemsetAsync(head, 0xFF, (size_t)BQ * NA * 4, stream);
  hipMemsetAsync(rescueCnt, 0, 256, stream);
  hipMemsetAsync(rescueKey, 0, (size_t)BQ * NA * 8, stream);

  k_metric<<<512, 256, 0, stream>>>(X, W, bias, ma, mb, maH, maM, mbH, mbM);
  k_scores_mfma<<<BQ * 64 * CSPL, 256, 0, stream>>>(maH, maM, mbH, mbM, pv1, pi1, pv2);
  k_merge8<<<(BQ * NA + 255) / 256, 256, 0, stream>>>(pv1, pi1, pv2, valA, nodeA, gapA);
  k_mark<<<BQ, 1024, 0, stream>>>(valA, gapA, rescueCnt, rescueIdx);
  k_rescue<<<BQ * 256, 256, 0, stream>>>(ma, mb, rescueIdx, rescueCnt, rescueKey);
  k_finalize<<<(BQ * NA + 255) / 256, 256, 0, stream>>>(rescueKey, valA, nodeA);
  k_topk<<<BQ, 1024, 0, stream>>>(valA, sel);
  k_build<<<(BQ * NA + 255) / 256, 256, 0, stream>>>(sel, nodeA, cnt, head, nxt);
  k_scan<<<BQ, 1024, 0, stream>>>(sel, nodeA, newidx, out + (size_t)BQ * NKEEP * CDIM);
  k_assemble<<<BQ * NTOK, 128, 0, stream>>>(X, sel, newidx, cnt, head, nxt, out);
}

// Round 7
// 362.839 us; speedup vs baseline: 1.6832x; 1.0483x over previous
//
#include <hip/hip_runtime.h>
#include <cstdint>
#include <cstddef>

#define BQ    4
#define NTOK  8192
#define CDIM  512
#define MDIM  128
#define NA    4096
#define RSEL  2048
#define NKEEP (NTOK - RSEL)   // 6144
#define RESCUE_CAP 2048
#define GAP_DELTA 2e-4f
#define WIN_TAU   2e-4f
#define CSPL  8

typedef float f32x4 __attribute__((ext_vector_type(4)));
typedef short short8 __attribute__((ext_vector_type(8)));

static __device__ __forceinline__ unsigned short bf16rne(float f) {
  unsigned u = __float_as_uint(f);
  return (unsigned short)((u + 0x7FFFu + ((u >> 16) & 1)) >> 16);
}

// ---------------------------------------------------------------------------
// K1: metric = x @ W^T + b, row-normalize, split even/odd rows into ma/mb
// (fp32) AND emit bf16 hi/mid planes.
// v4: 64 tokens x 128 outs per block, 128 THREADS, 8x8 micro-tile
// (16 ds_read_b128 per 256 FMA -> LDS-pipe floor 1.5x VALU, was 2.25x),
// K-chunk 32 double-buffered via global_load_lds w/ pre-swizzled source.
// Summation order over k unchanged (sequential) -> ma/mb bit-identical to v3.
// ---------------------------------------------------------------------------
__global__ __launch_bounds__(128) void k_metric(const float* __restrict__ X,
                                                const float* __restrict__ W,
                                                const float* __restrict__ bias,
                                                float* __restrict__ ma,
                                                float* __restrict__ mb,
                                                unsigned short* __restrict__ maH,
                                                unsigned short* __restrict__ maM,
                                                unsigned short* __restrict__ mbH,
                                                unsigned short* __restrict__ mbM) {
  __shared__ float ldsA[2][64 * 32];    // 8 KB per buf
  __shared__ float ldsB[2][128 * 32];   // 16 KB per buf
  __shared__ float snorm[64 * 16];
  __shared__ float sinv[64];
  const int t = threadIdx.x;            // 0..127
  const int tok0 = blockIdx.x * 64;
  const int r8 = t & 7, cg = t >> 3;    // row-lane (8), col-group (16)

  float acc[8][8];
#pragma unroll
  for (int i = 0; i < 8; ++i)
#pragma unroll
    for (int j = 0; j < 8; ++j) acc[i][j] = 0.f;

  // staging sources, pre-swizzled (LDS dest linear; swizzle on read matches)
  const char* aSrc[4];
  const char* bSrc[8];
#pragma unroll
  for (int i = 0; i < 4; ++i) {
    int s = i * 128 + t, row = s >> 3, gr = s & 7;
    aSrc[i] = (const char*)(X + (size_t)(tok0 + row) * CDIM) + ((gr ^ (row & 7)) << 4);
  }
#pragma unroll
  for (int i = 0; i < 8; ++i) {
    int s = i * 128 + t, row = s >> 3, gr = s & 7;
    bSrc[i] = (const char*)(W + (size_t)row * CDIM) + ((gr ^ ((row >> 3) & 7)) << 4);
  }

  auto stage = [&](int bufn, int kc) {
    const size_t off = (size_t)kc << 7;   // 32 floats = 128 B per chunk
    char* da = (char*)&ldsA[bufn][0] + t * 16;
    char* db = (char*)&ldsB[bufn][0] + t * 16;
#pragma unroll
    for (int i = 0; i < 4; ++i)
      __builtin_amdgcn_global_load_lds(
          (const __attribute__((address_space(1))) void*)(aSrc[i] + off),
          (__attribute__((address_space(3))) void*)(da + i * 2048), 16, 0, 0);
#pragma unroll
    for (int i = 0; i < 8; ++i)
      __builtin_amdgcn_global_load_lds(
          (const __attribute__((address_space(1))) void*)(bSrc[i] + off),
          (__attribute__((address_space(3))) void*)(db + i * 2048), 16, 0, 0);
  };

  auto compute = [&](int bufn) {
#pragma unroll
    for (int kq = 0; kq < 8; ++kq) {
      const int gA = (kq ^ r8) << 2;          // same granule for all av rows
      const int gB = (kq ^ (cg & 7)) << 2;    // same granule for all bv cols
      float4 av[8], bv[8];
#pragma unroll
      for (int i = 0; i < 8; ++i)
        av[i] = *(const float4*)&ldsA[bufn][(r8 + (i << 3)) * 32 + gA];
#pragma unroll
      for (int j = 0; j < 8; ++j)
        bv[j] = *(const float4*)&ldsB[bufn][((cg << 3) + j) * 32 + gB];
#pragma unroll
      for (int i = 0; i < 8; ++i)
#pragma unroll
        for (int j = 0; j < 8; ++j) {
          acc[i][j] = fmaf(av[i].x, bv[j].x, acc[i][j]);
          acc[i][j] = fmaf(av[i].y, bv[j].y, acc[i][j]);
          acc[i][j] = fmaf(av[i].z, bv[j].z, acc[i][j]);
          acc[i][j] = fmaf(av[i].w, bv[j].w, acc[i][j]);
        }
    }
  };

  stage(0, 0);
  __syncthreads();
  for (int kc = 0; kc < 16; ++kc) {
    if (kc + 1 < 16) stage((kc + 1) & 1, kc + 1);
    compute(kc & 1);
    __syncthreads();
  }

  float bb[8];
#pragma unroll
  for (int j = 0; j < 8; ++j) bb[j] = bias[(cg << 3) + j];
#pragma unroll
  for (int i = 0; i < 8; ++i) {
    float s = 0.f;
#pragma unroll
    for (int j = 0; j < 8; ++j) {
      acc[i][j] += bb[j];
      s = fmaf(acc[i][j], acc[i][j], s);
    }
    snorm[(r8 + (i << 3)) * 16 + cg] = s;
  }
  __syncthreads();
  if (t < 64) {
    float s = 0.f;
    for (int q = 0; q < 16; ++q) s += snorm[t * 16 + q];
    sinv[t] = 1.0f / sqrtf(s);
  }
  __syncthreads();
#pragma unroll
  for (int i = 0; i < 8; ++i) {
    int r = r8 + (i << 3);
    int tokg = tok0 + r;
    float inv = sinv[r];
    int bq = tokg >> 13, pos = tokg & (NTOK - 1);
    size_t eidx = ((size_t)bq * NA + (pos >> 1)) * MDIM + (cg << 3);
    float vv[8];
#pragma unroll
    for (int j = 0; j < 8; ++j) vv[j] = acc[i][j] * inv;
    float* dst = ((pos & 1) ? mb : ma) + eidx;
    *(float4*)dst = make_float4(vv[0], vv[1], vv[2], vv[3]);
    *(float4*)(dst + 4) = make_float4(vv[4], vv[5], vv[6], vv[7]);
    unsigned hB[8], mB[8];
#pragma unroll
    for (int j = 0; j < 8; ++j) {
      hB[j] = bf16rne(vv[j]);
      mB[j] = bf16rne(vv[j] - __uint_as_float(hB[j] << 16));
    }
    uint4 hw, mw;
    hw.x = hB[0] | (hB[1] << 16); hw.y = hB[2] | (hB[3] << 16);
    hw.z = hB[4] | (hB[5] << 16); hw.w = hB[6] | (hB[7] << 16);
    mw.x = mB[0] | (mB[1] << 16); mw.y = mB[2] | (mB[3] << 16);
    mw.z = mB[4] | (mB[5] << 16); mw.w = mB[6] | (mB[7] << 16);
    *(uint4*)(((pos & 1) ? mbH : maH) + eidx) = hw;
    *(uint4*)(((pos & 1) ? mbM : maM) + eidx) = mw;
  }
}

// ---------------------------------------------------------------------------
// K2: scores via split-bf16 MFMA (hi*hi + hi*mid + mid*hi), per-row top-2.
// (unchanged from round 6 — validated)
// ---------------------------------------------------------------------------
__global__ __launch_bounds__(256, 4) void k_scores_mfma(
    const unsigned short* __restrict__ maH, const unsigned short* __restrict__ maM,
    const unsigned short* __restrict__ mbH, const unsigned short* __restrict__ mbM,
    float* __restrict__ pv1, int* __restrict__ pi1, float* __restrict__ pv2) {
  __shared__ short8 lds8[2][2][32][16];
  const int t = threadIdx.x;
  const int bid = blockIdx.x;
  const int bq = bid >> 9, rem = bid & 511, at = rem >> 3, cs = rem & 7;
  const int a0 = at * 64;
  const int l = t & 63, w = t >> 6;
  const int l15 = l & 15, l4 = l >> 4, l7 = l & 7;

  short8 aH[4], aM[4];
#pragma unroll
  for (int kc = 0; kc < 4; ++kc) {
    size_t aidx = ((size_t)bq * NA + a0 + w * 16 + l15) * MDIM + kc * 32 + l4 * 8;
    aH[kc] = *(const short8*)(maH + aidx);
    aM[kc] = *(const short8*)(maM + aidx);
  }

  const unsigned short* bplane = (w >> 1) ? mbM : mbH;
  const char* sp0; const char* sp1; const char* sp2; const char* sp3;
  {
    const int clb = (w & 1) * 16 + l4;
    const size_t rowb = (size_t)bq * NA + cs * 512;
    sp0 = (const char*)bplane + ((rowb + clb +  0) << 8) + ((l15 ^ ((clb +  0) & 7)) << 4);
    sp1 = (const char*)bplane + ((rowb + clb +  4) << 8) + ((l15 ^ ((clb +  4) & 7)) << 4);
    sp2 = (const char*)bplane + ((rowb + clb +  8) << 8) + ((l15 ^ ((clb +  8) & 7)) << 4);
    sp3 = (const char*)bplane + ((rowb + clb + 12) << 8) + ((l15 ^ ((clb + 12) & 7)) << 4);
  }

  float bv1[4], bv2[4];
  int bi1[4];
#pragma unroll
  for (int s = 0; s < 4; ++s) { bv1[s] = -1e30f; bv2[s] = -1e30f; bi1[s] = 0x7FFFFFFF; }

  auto stage = [&](int bufn) {
    char* dst = (char*)&lds8[bufn][0][0][0] + w * 4096 + l * 16;
    __builtin_amdgcn_global_load_lds((const __attribute__((address_space(1))) void*)sp0,
        (__attribute__((address_space(3))) void*)(dst + 0),    16, 0, 0);
    __builtin_amdgcn_global_load_lds((const __attribute__((address_space(1))) void*)sp1,
        (__attribute__((address_space(3))) void*)(dst + 1024), 16, 0, 0);
    __builtin_amdgcn_global_load_lds((const __attribute__((address_space(1))) void*)sp2,
        (__attribute__((address_space(3))) void*)(dst + 2048), 16, 0, 0);
    __builtin_amdgcn_global_load_lds((const __attribute__((address_space(1))) void*)sp3,
        (__attribute__((address_space(3))) void*)(dst + 3072), 16, 0, 0);
    sp0 += 8192; sp1 += 8192; sp2 += 8192; sp3 += 8192;
  };

  auto compute = [&](int bufn, int cbase) {
    f32x4 acc1[2], acc2[2];
    acc1[0] = 0.f; acc1[1] = 0.f; acc2[0] = 0.f; acc2[1] = 0.f;
#pragma unroll
    for (int kc = 0; kc < 4; ++kc) {
      const int gg = (kc * 4 + l4) ^ l7;
#pragma unroll
      for (int cf = 0; cf < 2; ++cf) {
        short8 bh = lds8[bufn][0][cf * 16 + l15][gg];
        short8 bm = lds8[bufn][1][cf * 16 + l15][gg];
        acc1[cf] = __builtin_amdgcn_mfma_f32_16x16x32_bf16(aH[kc], bh, acc1[cf], 0, 0, 0);
        acc2[cf] = __builtin_amdgcn_mfma_f32_16x16x32_bf16(aH[kc], bm, acc2[cf], 0, 0, 0);
        acc2[cf] = __builtin_amdgcn_mfma_f32_16x16x32_bf16(aM[kc], bh, acc2[cf], 0, 0, 0);
      }
    }
#pragma unroll
    for (int cf = 0; cf < 2; ++cf) {
      const int cg = cbase + cf * 16 + l15;
      f32x4 v4 = acc1[cf] + acc2[cf];
#pragma unroll
      for (int r2 = 0; r2 < 4; ++r2) {
        float v = v4[r2];
        if (v > bv1[r2]) { bv2[r2] = bv1[r2]; bv1[r2] = v; bi1[r2] = cg; }
        else if (v > bv2[r2]) bv2[r2] = v;
      }
    }
  };

  stage(0);
  __syncthreads();
  const int cb0 = cs * 512;
  for (int chp = 0; chp < 8; ++chp) {
    const int ch = chp * 2;
    if (ch + 1 < 16) stage(1);
    compute(0, cb0 + ch * 32);
    __syncthreads();
    if (ch + 2 < 16) stage(0);
    compute(1, cb0 + ch * 32 + 32);
    __syncthreads();
  }

#pragma unroll
  for (int s = 0; s < 4; ++s) {
    float v1 = bv1[s], v2 = bv2[s];
    int i1 = bi1[s];
#pragma unroll
    for (int m = 1; m < 16; m <<= 1) {
      float V1 = __shfl_xor(v1, m);
      int I1 = __shfl_xor(i1, m);
      float V2 = __shfl_xor(v2, m);
      bool take = (V1 > v1) || (V1 == v1 && I1 < i1);
      float lose = take ? v1 : V1;
      if (take) { v1 = V1; i1 = I1; }
      v2 = fmaxf(fmaxf(v2, V2), lose);
    }
    if (l15 == s) {
      int row = a0 + w * 16 + l4 * 4 + s;
      size_t off = ((size_t)(bq * CSPL + cs)) * NA + row;
      pv1[off] = v1; pi1[off] = i1; pv2[off] = v2;
    }
  }
}

// ---------------------------------------------------------------------------
// K3 (fused): merge 8 csplit partials + init cnt/head/rescueKey/rescueCnt +
// bitonic sort -> rank-2048 value vb + mark rescue rows. One block per batch.
// Numerics identical to old k_merge8 + k_mark.
// ---------------------------------------------------------------------------
__global__ __launch_bounds__(1024) void k_mergemark(
    const float* __restrict__ pv1, const int* __restrict__ pi1,
    const float* __restrict__ pv2,
    float* __restrict__ valA, int* __restrict__ nodeA,
    int* __restrict__ rescueCnt, int* __restrict__ rescueIdx,
    int* __restrict__ cnt, int* __restrict__ head,
    unsigned long long* __restrict__ rescueKey) {
  __shared__ unsigned long long keys[NA];
  __shared__ float vbS;
  const int b = blockIdx.x, t = threadIdx.x;
  if (t == 0) rescueCnt[b] = 0;
  float gval[4], ggap[4];
#pragma unroll
  for (int k4 = 0; k4 < 4; ++k4) {
    const int p = t + k4 * 1024;
    const size_t i = (size_t)b * NA + p;
    float v1 = -1e30f, v2 = -1e30f;
    int i1 = 0x7FFFFFFF;
#pragma unroll
    for (int cspl = 0; cspl < CSPL; ++cspl) {
      size_t o = ((size_t)(b * CSPL + cspl)) * NA + p;
      float V1 = pv1[o], V2 = pv2[o];
      int I1 = pi1[o];
      bool take = (V1 > v1) || (V1 == v1 && I1 < i1);
      float lose = take ? v1 : V1;
      if (take) { v1 = V1; i1 = I1; }
      v2 = fmaxf(fmaxf(v2, V2), lose);
    }
    valA[i] = v1; nodeA[i] = i1;
    cnt[i] = 0; head[i] = -1; rescueKey[i] = 0ull;
    gval[k4] = v1; ggap[k4] = v1 - v2;
    unsigned u = __float_as_uint(v1);
    unsigned mono = u ^ ((u >> 31) ? 0xFFFFFFFFu : 0x80000000u);
    keys[p] = ((unsigned long long)(~mono) << 32) | (unsigned)p;
  }
  __syncthreads();
  for (int k = 2; k <= NA; k <<= 1) {
    for (int j = k >> 1; j > 0; j >>= 1) {
      for (int p = t; p < NA; p += 1024) {
        int q = p ^ j;
        if (q > p) {
          bool up = ((p & k) == 0);
          unsigned long long a = keys[p], c = keys[q];
          if ((a > c) == up) { keys[p] = c; keys[q] = a; }
        }
      }
      __syncthreads();
    }
  }
  if (t == 0) {
    unsigned mono = ~(unsigned)(keys[RSEL - 1] >> 32);
    unsigned u = (mono >> 31) ? (mono ^ 0x80000000u) : ~mono;
    vbS = __uint_as_float(u);
  }
  __syncthreads();
  const float vb = vbS;
#pragma unroll
  for (int k4 = 0; k4 < 4; ++k4) {
    const int p = t + k4 * 1024;
    if (ggap[k4] < GAP_DELTA || fabsf(gval[k4] - vb) <= WIN_TAU) {
      int slot = atomicAdd(&rescueCnt[b], 1);
      if (slot < RESCUE_CAP) rescueIdx[b * RESCUE_CAP + slot] = p;
    }
  }
}

// ---------------------------------------------------------------------------
// K4: exact fp32 recompute, parallel over (slot x 16 column-chunks).
// (unchanged from round 6 — validated)
// ---------------------------------------------------------------------------
__global__ __launch_bounds__(256) void k_rescue(const float* __restrict__ ma,
                                                const float* __restrict__ mb,
                                                const int* __restrict__ rescueIdx,
                                                const int* __restrict__ rescueCnt,
                                                unsigned long long* __restrict__ key) {
  const int bq = blockIdx.x >> 8;
  const int wid = blockIdx.x & 255;
  const int cnt = min(rescueCnt[bq], RESCUE_CAP);
  const int npair = cnt * 16;
  const int t = threadIdx.x;
  __shared__ float sA[128];
  __shared__ float wv[4];
  __shared__ int   wi[4];
  for (int pair = wid; pair < npair; pair += 256) {
    const int slot = pair >> 4, chunk = pair & 15;
    const int row = rescueIdx[bq * RESCUE_CAP + slot];
    __syncthreads();
    if (t < 128) sA[t] = ma[((size_t)bq * NA + row) * MDIM + t];
    __syncthreads();
    const int c = chunk * 256 + t;
    const float* bp = mb + ((size_t)bq * NA + c) * MDIM;
    float d0 = 0.f, d1 = 0.f, d2 = 0.f, d3 = 0.f;
#pragma unroll
    for (int j = 0; j < 8; ++j) {
      float4 b0 = *(const float4*)(bp + j * 16 + 0);
      float4 b1 = *(const float4*)(bp + j * 16 + 4);
      float4 b2 = *(const float4*)(bp + j * 16 + 8);
      float4 b3 = *(const float4*)(bp + j * 16 + 12);
      const float4 a0 = *(const float4*)&sA[j * 16 + 0];
      const float4 a1 = *(const float4*)&sA[j * 16 + 4];
      const float4 a2 = *(const float4*)&sA[j * 16 + 8];
      const float4 a3 = *(const float4*)&sA[j * 16 + 12];
      d0 = fmaf(a0.x, b0.x, d0); d0 = fmaf(a0.y, b0.y, d0);
      d0 = fmaf(a0.z, b0.z, d0); d0 = fmaf(a0.w, b0.w, d0);
      d1 = fmaf(a1.x, b1.x, d1); d1 = fmaf(a1.y, b1.y, d1);
      d1 = fmaf(a1.z, b1.z, d1); d1 = fmaf(a1.w, b1.w, d1);
      d2 = fmaf(a2.x, b2.x, d2); d2 = fmaf(a2.y, b2.y, d2);
      d2 = fmaf(a2.z, b2.z, d2); d2 = fmaf(a2.w, b2.w, d2);
      d3 = fmaf(a3.x, b3.x, d3); d3 = fmaf(a3.y, b3.y, d3);
      d3 = fmaf(a3.z, b3.z, d3); d3 = fmaf(a3.w, b3.w, d3);
    }
    float d = (d0 + d1) + (d2 + d3);
    int ci = c;
#pragma unroll
    for (int m = 1; m < 64; m <<= 1) {
      float V = __shfl_xor(d, m);
      int C = __shfl_xor(ci, m);
      if (V > d || (V == d && C < ci)) { d = V; ci = C; }
    }
    if ((t & 63) == 0) { wv[t >> 6] = d; wi[t >> 6] = ci; }
    __syncthreads();
    if (t == 0) {
      for (int w2 = 1; w2 < 4; ++w2)
        if (wv[w2] > d || (wv[w2] == d && wi[w2] < ci)) { d = wv[w2]; ci = wi[w2]; }
      unsigned u = __float_as_uint(d);
      unsigned mono = u ^ ((u >> 31) ? 0xFFFFFFFFu : 0x80000000u);
      unsigned long long k = ((unsigned long long)mono << 32)
                           | (unsigned)(0xFFFFFFFFu - (unsigned)ci);
      atomicMax(&key[(size_t)bq * NA + row], k);
    }
  }
}

// ---------------------------------------------------------------------------
// K5 (fused): decode rescued keys + exact top-2048 bitonic partition + build
// merge lists (cnt/head/nxt) + mask scan -> newidx + ownership output.
// One block per batch. Numerics identical to old finalize/topk/build/scan.
// ---------------------------------------------------------------------------
__global__ __launch_bounds__(1024) void k_select(
    const unsigned long long* __restrict__ rescueKey,
    const float* __restrict__ valA, const int* __restrict__ nodeA,
    int* __restrict__ sel, int* __restrict__ cnt, int* __restrict__ head,
    int* __restrict__ nxt, int* __restrict__ newidx,
    float* __restrict__ own) {
  __shared__ unsigned long long keys[NA];   // 32 KB
  __shared__ int nodeL[NA];                 // 16 KB
  __shared__ unsigned char selL[NA];        // 4 KB
  __shared__ int ni[NTOK];                  // 32 KB
  __shared__ int tot[1024];                 // 4 KB
  const int b = blockIdx.x, t = threadIdx.x;

  // 1) load + patch rescued rows
#pragma unroll
  for (int k4 = 0; k4 < 4; ++k4) {
    const int p = t + k4 * 1024;
    const size_t i = (size_t)b * NA + p;
    unsigned long long rk = rescueKey[i];
    float v; int nd;
    if (rk) {
      unsigned mono = (unsigned)(rk >> 32);
      unsigned u = (mono & 0x80000000u) ? (mono ^ 0x80000000u) : ~mono;
      v = __uint_as_float(u);
      nd = (int)(0xFFFFFFFFu - (unsigned)(rk & 0xFFFFFFFFull));
    } else {
      v = valA[i];
      nd = nodeA[i];
    }
    nodeL[p] = nd;
    unsigned u = __float_as_uint(v);
    unsigned mono = u ^ ((u >> 31) ? 0xFFFFFFFFu : 0x80000000u);
    keys[p] = ((unsigned long long)(~mono) << 32) | (unsigned)p;
  }
  __syncthreads();

  // 2) bitonic sort (desc value, asc idx) — exact top_k partition
  for (int k = 2; k <= NA; k <<= 1) {
    for (int j = k >> 1; j > 0; j >>= 1) {
      for (int p = t; p < NA; p += 1024) {
        int q = p ^ j;
        if (q > p) {
          bool up = ((p & k) == 0);
          unsigned long long a = keys[p], c = keys[q];
          if ((a > c) == up) { keys[p] = c; keys[q] = a; }
        }
      }
      __syncthreads();
    }
  }

  // 3) selection mask
#pragma unroll
  for (int k4 = 0; k4 < 4; ++k4) {
    const int p = t + k4 * 1024;
    int idx = (int)(keys[p] & 0xFFFFFFFFull);
    selL[idx] = (p < RSEL) ? 1 : 0;
  }
  __syncthreads();

  // 4) sel to global + build merge lists
#pragma unroll
  for (int k4 = 0; k4 < 4; ++k4) {
    const int p = t + k4 * 1024;
    const size_t i = (size_t)b * NA + p;
    int s = selL[p];
    sel[i] = s;
    if (s) {
      int dst = nodeL[p];
      atomicAdd(&cnt[(size_t)b * NA + dst], 1);
      nxt[i] = atomicExch(&head[(size_t)b * NA + dst], p);
    }
  }

  // 5) mask scan over 8192 positions -> newidx + ownership
  const int base = t * 8;
  int kept[8], run = 0;
#pragma unroll
  for (int e = 0; e < 8; ++e) {
    int idx = base + e;
    int kp = ((idx & 1) == 0) ? 1 : (selL[idx >> 1] ? 0 : 1);
    kept[e] = kp;
    run += kp;
  }
  tot[t] = run;
  __syncthreads();
  for (int off = 1; off < 1024; off <<= 1) {
    int v = (t >= off) ? tot[t - off] : 0;
    __syncthreads();
    tot[t] += v;
    __syncthreads();
  }
  int cum = tot[t] - run;
#pragma unroll
  for (int e = 0; e < 8; ++e) {
    cum += kept[e];
    ni[base + e] = cum - 1;
  }
  __syncthreads();
#pragma unroll
  for (int e = 0; e < 8; ++e) {
    int idx = base + e;
    int ow = kept[e] ? ni[idx] : ni[2 * nodeL[idx >> 1]];
    newidx[(size_t)b * NTOK + idx] = ni[idx];
    own[(size_t)b * NTOK + idx] = (float)ow;
  }
}

// ---------------------------------------------------------------------------
// K6: assemble x_final f32 (gather merges via linked list, divide, compact).
// 2 tokens per 256-thread block.
// ---------------------------------------------------------------------------
__global__ __launch_bounds__(256) void k_assemble(const float* __restrict__ X,
                                                  const int* __restrict__ sel,
                                                  const int* __restrict__ newidx,
                                                  const int* __restrict__ cnt,
                                                  const int* __restrict__ head,
                                                  const int* __restrict__ nxt,
                                                  float* __restrict__ out) {
  const int token = blockIdx.x * 2 + (threadIdx.x >> 7);
  const int bq = token >> 13, tp = token & (NTOK - 1);
  const int t = threadIdx.x & 127;
  if ((tp & 1) && sel[(size_t)bq * NA + (tp >> 1)]) return;
  float4 v = *(const float4*)(X + (size_t)token * CDIM + t * 4);
  if (!(tp & 1)) {
    size_t slot = (size_t)bq * NA + (tp >> 1);
    int c = cnt[slot];
    if (c > 0) {
      int kk = head[slot];
      while (kk >= 0) {
        float4 s = *(const float4*)(X + ((size_t)bq * NTOK + 2 * kk + 1) * CDIM + t * 4);
        v.x += s.x; v.y += s.y; v.z += s.z; v.w += s.w;
        kk = nxt[(size_t)bq * NA + kk];
      }
      float inv = 1.0f / (float)(1 + c);
      v.x *= inv; v.y *= inv; v.z *= inv; v.w *= inv;
    }
  }
  int dst = newidx[(size_t)bq * NTOK + tp];
  *(float4*)(out + ((size_t)bq * NKEEP + dst) * CDIM + t * 4) = v;
}

// ---------------------------------------------------------------------------
extern "C" void kernel_launch(void* const* d_in, const int* in_sizes, int n_in,
                              void* d_out, int out_size, void* d_ws, size_t ws_size,
                              hipStream_t stream) {
  const float* X    = (const float*)d_in[0];
  const float* W    = (const float*)d_in[1];
  const float* bias = (const float*)d_in[2];
  float* out = (float*)d_out;  // f32: x_final (4,6144,512) ++ ownership (4,8192)
  char* ws = (char*)d_ws;

  size_t o = 0;
  float* ma   = (float*)(ws + o); o += (size_t)BQ * NA * MDIM * 4;
  float* mb   = (float*)(ws + o); o += (size_t)BQ * NA * MDIM * 4;
  unsigned short* maH = (unsigned short*)(ws + o); o += (size_t)BQ * NA * MDIM * 2;
  unsigned short* maM = (unsigned short*)(ws + o); o += (size_t)BQ * NA * MDIM * 2;
  unsigned short* mbH = (unsigned short*)(ws + o); o += (size_t)BQ * NA * MDIM * 2;
  unsigned short* mbM = (unsigned short*)(ws + o); o += (size_t)BQ * NA * MDIM * 2;
  float* pv1  = (float*)(ws + o); o += (size_t)BQ * CSPL * NA * 4;
  int*   pi1  = (int*)(ws + o);   o += (size_t)BQ * CSPL * NA * 4;
  float* pv2  = (float*)(ws + o); o += (size_t)BQ * CSPL * NA * 4;
  float* valA = (float*)(ws + o); o += (size_t)BQ * NA * 4;
  int*   nodeA= (int*)(ws + o);   o += (size_t)BQ * NA * 4;
  int*   sel  = (int*)(ws + o);   o += (size_t)BQ * NA * 4;
  int*   cnt  = (int*)(ws + o);   o += (size_t)BQ * NA * 4;
  int*   head = (int*)(ws + o);   o += (size_t)BQ * NA * 4;
  int*   nxt  = (int*)(ws + o);   o += (size_t)BQ * NA * 4;
  int*   newidx = (int*)(ws + o); o += (size_t)BQ * NTOK * 4;
  int*   rescueCnt = (int*)(ws + o); o += 256;
  int*   rescueIdx = (int*)(ws + o); o += (size_t)BQ * RESCUE_CAP * 4;
  unsigned long long* rescueKey = (unsigned long long*)(ws + o); o += (size_t)BQ * NA * 8;
  (void)in_sizes; (void)n_in; (void)out_size; (void)ws_size;

  k_metric<<<512, 128, 0, stream>>>(X, W, bias, ma, mb, maH, maM, mbH, mbM);
  k_scores_mfma<<<BQ * 64 * CSPL, 256, 0, stream>>>(maH, maM, mbH, mbM, pv1, pi1, pv2);
  k_mergemark<<<BQ, 1024, 0, stream>>>(pv1, pi1, pv2, valA, nodeA,
                                       rescueCnt, rescueIdx, cnt, head, rescueKey);
  k_rescue<<<BQ * 256, 256, 0, stream>>>(ma, mb, rescueIdx, rescueCnt, rescueKey);
  k_select<<<BQ, 1024, 0, stream>>>(rescueKey, valA, nodeA, sel, cnt, head, nxt,
                                    newidx, out + (size_t)BQ * NKEEP * CDIM);
  k_assemble<<<BQ * NTOK / 2, 256, 0, stream>>>(X, sel, newidx, cnt, head, nxt, out);
}

// Round 8
// 274.157 us; speedup vs baseline: 2.2276x; 1.3235x over previous
//
#include <hip/hip_runtime.h>
#include <cstdint>
#include <cstddef>

#define BQ    4
#define NTOK  8192
#define CDIM  512
#define MDIM  128
#define NA    4096
#define RSEL  2048
#define NKEEP (NTOK - RSEL)   // 6144
#define RESCUE_CAP 2048
#define GAP_DELTA 2e-4f
#define WIN_TAU   2e-4f
#define CSPL  8

typedef float f32x4 __attribute__((ext_vector_type(4)));
typedef short short8 __attribute__((ext_vector_type(8)));

static __device__ __forceinline__ unsigned short bf16rne(float f) {
  unsigned u = __float_as_uint(f);
  return (unsigned short)((u + 0x7FFFu + ((u >> 16) & 1)) >> 16);
}

// ---------------------------------------------------------------------------
// rank_select_4096: exact (rank)-th smallest (0-indexed) of 4096 UNIQUE u64
// keys resident in LDS, without sorting them. 3-level 12-bit radix cascade:
// after 3 levels the 36-bit prefix pins the 32-bit value + top idx bits, so
// <=16 keys can match -> candidate set always fits candL. keysL is preserved.
// All 1024 threads participate.
// ---------------------------------------------------------------------------
__device__ __forceinline__ unsigned long long rank_select_4096(
    const unsigned long long* keysL, unsigned* histL,
    unsigned long long* candL, unsigned* scanL, unsigned* shw /*[4]*/,
    int rank, int t) {
  unsigned long long pval = 0ull, pmask = 0ull;
  int curRank = rank;
  for (int lvl = 0; lvl < 3; ++lvl) {
    const int shift = 52 - lvl * 12;
#pragma unroll
    for (int i = 0; i < 4; ++i) histL[t + i * 1024] = 0;
    __syncthreads();
#pragma unroll
    for (int i = 0; i < 4; ++i) {
      unsigned long long k = keysL[t + i * 1024];
      if ((k & pmask) == pval)
        atomicAdd(&histL[(unsigned)((k >> shift) & 0xFFFull)], 1u);
    }
    __syncthreads();
    unsigned s = histL[4 * t] + histL[4 * t + 1] + histL[4 * t + 2] + histL[4 * t + 3];
    scanL[t] = s;
    __syncthreads();
    for (int off = 1; off < 1024; off <<= 1) {
      unsigned v = (t >= off) ? scanL[t - off] : 0;
      __syncthreads();
      scanL[t] += v;
      __syncthreads();
    }
    const unsigned incl = scanL[t], excl = incl - s;
    if ((int)excl <= curRank && curRank < (int)incl) {
      int r = curRank - (int)excl;
      unsigned b = 4 * t;
#pragma unroll
      for (int q = 0; q < 4; ++q) {
        unsigned c = histL[4 * t + q];
        if (r < (int)c) { b = 4 * t + q; break; }
        r -= (int)c;
      }
      shw[0] = b; shw[1] = (unsigned)r; shw[3] = histL[b];
    }
    __syncthreads();
    const unsigned bucket = shw[0];
    curRank = (int)shw[1];
    const unsigned cntB = shw[3];
    pval |= ((unsigned long long)bucket) << shift;
    pmask |= 0xFFFull << shift;
    if (cntB <= 1024u) break;
  }
  if (t == 0) shw[2] = 0;
  __syncthreads();
#pragma unroll
  for (int i = 0; i < 4; ++i) {
    unsigned long long k = keysL[t + i * 1024];
    if ((k & pmask) == pval) {
      unsigned pos = atomicAdd(&shw[2], 1u);
      if (pos < 1024u) candL[pos] = k;
    }
  }
  __syncthreads();
  const int c1 = (int)shw[2];
  int P = 64;
  while (P < c1) P <<= 1;
  for (int p = t; p < P; p += 1024)
    if (p >= c1) candL[p] = ~0ull;
  __syncthreads();
  for (int k2 = 2; k2 <= P; k2 <<= 1)
    for (int j = k2 >> 1; j > 0; j >>= 1) {
      for (int p = t; p < P; p += 1024) {
        int q = p ^ j;
        if (q > p) {
          bool up = ((p & k2) == 0);
          unsigned long long a = candL[p], c = candL[q];
          if ((a > c) == up) { candL[p] = c; candL[q] = a; }
        }
      }
      __syncthreads();
    }
  return candL[curRank];
}

// ---------------------------------------------------------------------------
// K1: metric = x @ W^T + b, row-normalize, split even/odd rows into ma/mb
// (fp32) AND emit bf16 hi/mid planes. (validated round-7 version, unchanged)
// ---------------------------------------------------------------------------
__global__ __launch_bounds__(128) void k_metric(const float* __restrict__ X,
                                                const float* __restrict__ W,
                                                const float* __restrict__ bias,
                                                float* __restrict__ ma,
                                                float* __restrict__ mb,
                                                unsigned short* __restrict__ maH,
                                                unsigned short* __restrict__ maM,
                                                unsigned short* __restrict__ mbH,
                                                unsigned short* __restrict__ mbM) {
  __shared__ float ldsA[2][64 * 32];
  __shared__ float ldsB[2][128 * 32];
  __shared__ float snorm[64 * 16];
  __shared__ float sinv[64];
  const int t = threadIdx.x;
  const int tok0 = blockIdx.x * 64;
  const int r8 = t & 7, cg = t >> 3;

  float acc[8][8];
#pragma unroll
  for (int i = 0; i < 8; ++i)
#pragma unroll
    for (int j = 0; j < 8; ++j) acc[i][j] = 0.f;

  const char* aSrc[4];
  const char* bSrc[8];
#pragma unroll
  for (int i = 0; i < 4; ++i) {
    int s = i * 128 + t, row = s >> 3, gr = s & 7;
    aSrc[i] = (const char*)(X + (size_t)(tok0 + row) * CDIM) + ((gr ^ (row & 7)) << 4);
  }
#pragma unroll
  for (int i = 0; i < 8; ++i) {
    int s = i * 128 + t, row = s >> 3, gr = s & 7;
    bSrc[i] = (const char*)(W + (size_t)row * CDIM) + ((gr ^ ((row >> 3) & 7)) << 4);
  }

  auto stage = [&](int bufn, int kc) {
    const size_t off = (size_t)kc << 7;
    char* da = (char*)&ldsA[bufn][0] + t * 16;
    char* db = (char*)&ldsB[bufn][0] + t * 16;
#pragma unroll
    for (int i = 0; i < 4; ++i)
      __builtin_amdgcn_global_load_lds(
          (const __attribute__((address_space(1))) void*)(aSrc[i] + off),
          (__attribute__((address_space(3))) void*)(da + i * 2048), 16, 0, 0);
#pragma unroll
    for (int i = 0; i < 8; ++i)
      __builtin_amdgcn_global_load_lds(
          (const __attribute__((address_space(1))) void*)(bSrc[i] + off),
          (__attribute__((address_space(3))) void*)(db + i * 2048), 16, 0, 0);
  };

  auto compute = [&](int bufn) {
#pragma unroll
    for (int kq = 0; kq < 8; ++kq) {
      const int gA = (kq ^ r8) << 2;
      const int gB = (kq ^ (cg & 7)) << 2;
      float4 av[8], bv[8];
#pragma unroll
      for (int i = 0; i < 8; ++i)
        av[i] = *(const float4*)&ldsA[bufn][(r8 + (i << 3)) * 32 + gA];
#pragma unroll
      for (int j = 0; j < 8; ++j)
        bv[j] = *(const float4*)&ldsB[bufn][((cg << 3) + j) * 32 + gB];
#pragma unroll
      for (int i = 0; i < 8; ++i)
#pragma unroll
        for (int j = 0; j < 8; ++j) {
          acc[i][j] = fmaf(av[i].x, bv[j].x, acc[i][j]);
          acc[i][j] = fmaf(av[i].y, bv[j].y, acc[i][j]);
          acc[i][j] = fmaf(av[i].z, bv[j].z, acc[i][j]);
          acc[i][j] = fmaf(av[i].w, bv[j].w, acc[i][j]);
        }
    }
  };

  stage(0, 0);
  __syncthreads();
  for (int kc = 0; kc < 16; ++kc) {
    if (kc + 1 < 16) stage((kc + 1) & 1, kc + 1);
    compute(kc & 1);
    __syncthreads();
  }

  float bb[8];
#pragma unroll
  for (int j = 0; j < 8; ++j) bb[j] = bias[(cg << 3) + j];
#pragma unroll
  for (int i = 0; i < 8; ++i) {
    float s = 0.f;
#pragma unroll
    for (int j = 0; j < 8; ++j) {
      acc[i][j] += bb[j];
      s = fmaf(acc[i][j], acc[i][j], s);
    }
    snorm[(r8 + (i << 3)) * 16 + cg] = s;
  }
  __syncthreads();
  if (t < 64) {
    float s = 0.f;
    for (int q = 0; q < 16; ++q) s += snorm[t * 16 + q];
    sinv[t] = 1.0f / sqrtf(s);
  }
  __syncthreads();
#pragma unroll
  for (int i = 0; i < 8; ++i) {
    int r = r8 + (i << 3);
    int tokg = tok0 + r;
    float inv = sinv[r];
    int bq = tokg >> 13, pos = tokg & (NTOK - 1);
    size_t eidx = ((size_t)bq * NA + (pos >> 1)) * MDIM + (cg << 3);
    float vv[8];
#pragma unroll
    for (int j = 0; j < 8; ++j) vv[j] = acc[i][j] * inv;
    float* dst = ((pos & 1) ? mb : ma) + eidx;
    *(float4*)dst = make_float4(vv[0], vv[1], vv[2], vv[3]);
    *(float4*)(dst + 4) = make_float4(vv[4], vv[5], vv[6], vv[7]);
    unsigned hB[8], mB[8];
#pragma unroll
    for (int j = 0; j < 8; ++j) {
      hB[j] = bf16rne(vv[j]);
      mB[j] = bf16rne(vv[j] - __uint_as_float(hB[j] << 16));
    }
    uint4 hw, mw;
    hw.x = hB[0] | (hB[1] << 16); hw.y = hB[2] | (hB[3] << 16);
    hw.z = hB[4] | (hB[5] << 16); hw.w = hB[6] | (hB[7] << 16);
    mw.x = mB[0] | (mB[1] << 16); mw.y = mB[2] | (mB[3] << 16);
    mw.z = mB[4] | (mB[5] << 16); mw.w = mB[6] | (mB[7] << 16);
    *(uint4*)(((pos & 1) ? mbH : maH) + eidx) = hw;
    *(uint4*)(((pos & 1) ? mbM : maM) + eidx) = mw;
  }
}

// ---------------------------------------------------------------------------
// K2: scores via split-bf16 MFMA (hi*hi + hi*mid + mid*hi), per-row top-2.
// (validated round-6/7 version, unchanged)
// ---------------------------------------------------------------------------
__global__ __launch_bounds__(256, 4) void k_scores_mfma(
    const unsigned short* __restrict__ maH, const unsigned short* __restrict__ maM,
    const unsigned short* __restrict__ mbH, const unsigned short* __restrict__ mbM,
    float* __restrict__ pv1, int* __restrict__ pi1, float* __restrict__ pv2) {
  __shared__ short8 lds8[2][2][32][16];
  const int t = threadIdx.x;
  const int bid = blockIdx.x;
  const int bq = bid >> 9, rem = bid & 511, at = rem >> 3, cs = rem & 7;
  const int a0 = at * 64;
  const int l = t & 63, w = t >> 6;
  const int l15 = l & 15, l4 = l >> 4, l7 = l & 7;

  short8 aH[4], aM[4];
#pragma unroll
  for (int kc = 0; kc < 4; ++kc) {
    size_t aidx = ((size_t)bq * NA + a0 + w * 16 + l15) * MDIM + kc * 32 + l4 * 8;
    aH[kc] = *(const short8*)(maH + aidx);
    aM[kc] = *(const short8*)(maM + aidx);
  }

  const unsigned short* bplane = (w >> 1) ? mbM : mbH;
  const char* sp0; const char* sp1; const char* sp2; const char* sp3;
  {
    const int clb = (w & 1) * 16 + l4;
    const size_t rowb = (size_t)bq * NA + cs * 512;
    sp0 = (const char*)bplane + ((rowb + clb +  0) << 8) + ((l15 ^ ((clb +  0) & 7)) << 4);
    sp1 = (const char*)bplane + ((rowb + clb +  4) << 8) + ((l15 ^ ((clb +  4) & 7)) << 4);
    sp2 = (const char*)bplane + ((rowb + clb +  8) << 8) + ((l15 ^ ((clb +  8) & 7)) << 4);
    sp3 = (const char*)bplane + ((rowb + clb + 12) << 8) + ((l15 ^ ((clb + 12) & 7)) << 4);
  }

  float bv1[4], bv2[4];
  int bi1[4];
#pragma unroll
  for (int s = 0; s < 4; ++s) { bv1[s] = -1e30f; bv2[s] = -1e30f; bi1[s] = 0x7FFFFFFF; }

  auto stage = [&](int bufn) {
    char* dst = (char*)&lds8[bufn][0][0][0] + w * 4096 + l * 16;
    __builtin_amdgcn_global_load_lds((const __attribute__((address_space(1))) void*)sp0,
        (__attribute__((address_space(3))) void*)(dst + 0),    16, 0, 0);
    __builtin_amdgcn_global_load_lds((const __attribute__((address_space(1))) void*)sp1,
        (__attribute__((address_space(3))) void*)(dst + 1024), 16, 0, 0);
    __builtin_amdgcn_global_load_lds((const __attribute__((address_space(1))) void*)sp2,
        (__attribute__((address_space(3))) void*)(dst + 2048), 16, 0, 0);
    __builtin_amdgcn_global_load_lds((const __attribute__((address_space(1))) void*)sp3,
        (__attribute__((address_space(3))) void*)(dst + 3072), 16, 0, 0);
    sp0 += 8192; sp1 += 8192; sp2 += 8192; sp3 += 8192;
  };

  auto compute = [&](int bufn, int cbase) {
    f32x4 acc1[2], acc2[2];
    acc1[0] = 0.f; acc1[1] = 0.f; acc2[0] = 0.f; acc2[1] = 0.f;
#pragma unroll
    for (int kc = 0; kc < 4; ++kc) {
      const int gg = (kc * 4 + l4) ^ l7;
#pragma unroll
      for (int cf = 0; cf < 2; ++cf) {
        short8 bh = lds8[bufn][0][cf * 16 + l15][gg];
        short8 bm = lds8[bufn][1][cf * 16 + l15][gg];
        acc1[cf] = __builtin_amdgcn_mfma_f32_16x16x32_bf16(aH[kc], bh, acc1[cf], 0, 0, 0);
        acc2[cf] = __builtin_amdgcn_mfma_f32_16x16x32_bf16(aH[kc], bm, acc2[cf], 0, 0, 0);
        acc2[cf] = __builtin_amdgcn_mfma_f32_16x16x32_bf16(aM[kc], bh, acc2[cf], 0, 0, 0);
      }
    }
#pragma unroll
    for (int cf = 0; cf < 2; ++cf) {
      const int cg = cbase + cf * 16 + l15;
      f32x4 v4 = acc1[cf] + acc2[cf];
#pragma unroll
      for (int r2 = 0; r2 < 4; ++r2) {
        float v = v4[r2];
        if (v > bv1[r2]) { bv2[r2] = bv1[r2]; bv1[r2] = v; bi1[r2] = cg; }
        else if (v > bv2[r2]) bv2[r2] = v;
      }
    }
  };

  stage(0);
  __syncthreads();
  const int cb0 = cs * 512;
  for (int chp = 0; chp < 8; ++chp) {
    const int ch = chp * 2;
    if (ch + 1 < 16) stage(1);
    compute(0, cb0 + ch * 32);
    __syncthreads();
    if (ch + 2 < 16) stage(0);
    compute(1, cb0 + ch * 32 + 32);
    __syncthreads();
  }

#pragma unroll
  for (int s = 0; s < 4; ++s) {
    float v1 = bv1[s], v2 = bv2[s];
    int i1 = bi1[s];
#pragma unroll
    for (int m = 1; m < 16; m <<= 1) {
      float V1 = __shfl_xor(v1, m);
      int I1 = __shfl_xor(i1, m);
      float V2 = __shfl_xor(v2, m);
      bool take = (V1 > v1) || (V1 == v1 && I1 < i1);
      float lose = take ? v1 : V1;
      if (take) { v1 = V1; i1 = I1; }
      v2 = fmaxf(fmaxf(v2, V2), lose);
    }
    if (l15 == s) {
      int row = a0 + w * 16 + l4 * 4 + s;
      size_t off = ((size_t)(bq * CSPL + cs)) * NA + row;
      pv1[off] = v1; pi1[off] = i1; pv2[off] = v2;
    }
  }
}

// ---------------------------------------------------------------------------
// K3 (fused): merge 8 csplit partials + init cnt/head/rescueKey/rescueCnt +
// radix rank-select -> rank-2048 value vb + mark rescue rows. One block/batch.
// vb is EXACT (same key as old sorted keys[RSEL-1]) — marking unchanged.
// ---------------------------------------------------------------------------
__global__ __launch_bounds__(1024) void k_mergemark(
    const float* __restrict__ pv1, const int* __restrict__ pi1,
    const float* __restrict__ pv2,
    float* __restrict__ valA, int* __restrict__ nodeA,
    int* __restrict__ rescueCnt, int* __restrict__ rescueIdx,
    int* __restrict__ cnt, int* __restrict__ head,
    unsigned long long* __restrict__ rescueKey) {
  __shared__ unsigned long long keys[NA];   // 32 KB
  __shared__ unsigned hist[NA];             // 16 KB
  __shared__ unsigned long long cand[1024]; // 8 KB
  __shared__ unsigned scan1[1024];          // 4 KB
  __shared__ unsigned shw[4];
  const int b = blockIdx.x, t = threadIdx.x;
  if (t == 0) rescueCnt[b] = 0;
  float gval[4], ggap[4];
#pragma unroll
  for (int k4 = 0; k4 < 4; ++k4) {
    const int p = t + k4 * 1024;
    const size_t i = (size_t)b * NA + p;
    float v1 = -1e30f, v2 = -1e30f;
    int i1 = 0x7FFFFFFF;
#pragma unroll
    for (int cspl = 0; cspl < CSPL; ++cspl) {
      size_t o = ((size_t)(b * CSPL + cspl)) * NA + p;
      float V1 = pv1[o], V2 = pv2[o];
      int I1 = pi1[o];
      bool take = (V1 > v1) || (V1 == v1 && I1 < i1);
      float lose = take ? v1 : V1;
      if (take) { v1 = V1; i1 = I1; }
      v2 = fmaxf(fmaxf(v2, V2), lose);
    }
    valA[i] = v1; nodeA[i] = i1;
    cnt[i] = 0; head[i] = -1; rescueKey[i] = 0ull;
    gval[k4] = v1; ggap[k4] = v1 - v2;
    unsigned u = __float_as_uint(v1);
    unsigned mono = u ^ ((u >> 31) ? 0xFFFFFFFFu : 0x80000000u);
    keys[p] = ((unsigned long long)(~mono) << 32) | (unsigned)p;
  }
  __syncthreads();

  const unsigned long long thr =
      rank_select_4096(keys, hist, cand, scan1, shw, RSEL - 1, t);
  unsigned monoT = ~(unsigned)(thr >> 32);
  unsigned uT = (monoT >> 31) ? (monoT ^ 0x80000000u) : ~monoT;
  const float vb = __uint_as_float(uT);

#pragma unroll
  for (int k4 = 0; k4 < 4; ++k4) {
    const int p = t + k4 * 1024;
    if (ggap[k4] < GAP_DELTA || fabsf(gval[k4] - vb) <= WIN_TAU) {
      int slot = atomicAdd(&rescueCnt[b], 1);
      if (slot < RESCUE_CAP) rescueIdx[b * RESCUE_CAP + slot] = p;
    }
  }
}

// ---------------------------------------------------------------------------
// K4: exact fp32 recompute, parallel over (slot x 16 column-chunks).
// (validated, unchanged)
// ---------------------------------------------------------------------------
__global__ __launch_bounds__(256) void k_rescue(const float* __restrict__ ma,
                                                const float* __restrict__ mb,
                                                const int* __restrict__ rescueIdx,
                                                const int* __restrict__ rescueCnt,
                                                unsigned long long* __restrict__ key) {
  const int bq = blockIdx.x >> 8;
  const int wid = blockIdx.x & 255;
  const int cnt = min(rescueCnt[bq], RESCUE_CAP);
  const int npair = cnt * 16;
  const int t = threadIdx.x;
  __shared__ float sA[128];
  __shared__ float wv[4];
  __shared__ int   wi[4];
  for (int pair = wid; pair < npair; pair += 256) {
    const int slot = pair >> 4, chunk = pair & 15;
    const int row = rescueIdx[bq * RESCUE_CAP + slot];
    __syncthreads();
    if (t < 128) sA[t] = ma[((size_t)bq * NA + row) * MDIM + t];
    __syncthreads();
    const int c = chunk * 256 + t;
    const float* bp = mb + ((size_t)bq * NA + c) * MDIM;
    float d0 = 0.f, d1 = 0.f, d2 = 0.f, d3 = 0.f;
#pragma unroll
    for (int j = 0; j < 8; ++j) {
      float4 b0 = *(const float4*)(bp + j * 16 + 0);
      float4 b1 = *(const float4*)(bp + j * 16 + 4);
      float4 b2 = *(const float4*)(bp + j * 16 + 8);
      float4 b3 = *(const float4*)(bp + j * 16 + 12);
      const float4 a0 = *(const float4*)&sA[j * 16 + 0];
      const float4 a1 = *(const float4*)&sA[j * 16 + 4];
      const float4 a2 = *(const float4*)&sA[j * 16 + 8];
      const float4 a3 = *(const float4*)&sA[j * 16 + 12];
      d0 = fmaf(a0.x, b0.x, d0); d0 = fmaf(a0.y, b0.y, d0);
      d0 = fmaf(a0.z, b0.z, d0); d0 = fmaf(a0.w, b0.w, d0);
      d1 = fmaf(a1.x, b1.x, d1); d1 = fmaf(a1.y, b1.y, d1);
      d1 = fmaf(a1.z, b1.z, d1); d1 = fmaf(a1.w, b1.w, d1);
      d2 = fmaf(a2.x, b2.x, d2); d2 = fmaf(a2.y, b2.y, d2);
      d2 = fmaf(a2.z, b2.z, d2); d2 = fmaf(a2.w, b2.w, d2);
      d3 = fmaf(a3.x, b3.x, d3); d3 = fmaf(a3.y, b3.y, d3);
      d3 = fmaf(a3.z, b3.z, d3); d3 = fmaf(a3.w, b3.w, d3);
    }
    float d = (d0 + d1) + (d2 + d3);
    int ci = c;
#pragma unroll
    for (int m = 1; m < 64; m <<= 1) {
      float V = __shfl_xor(d, m);
      int C = __shfl_xor(ci, m);
      if (V > d || (V == d && C < ci)) { d = V; ci = C; }
    }
    if ((t & 63) == 0) { wv[t >> 6] = d; wi[t >> 6] = ci; }
    __syncthreads();
    if (t == 0) {
      for (int w2 = 1; w2 < 4; ++w2)
        if (wv[w2] > d || (wv[w2] == d && wi[w2] < ci)) { d = wv[w2]; ci = wi[w2]; }
      unsigned u = __float_as_uint(d);
      unsigned mono = u ^ ((u >> 31) ? 0xFFFFFFFFu : 0x80000000u);
      unsigned long long k = ((unsigned long long)mono << 32)
                           | (unsigned)(0xFFFFFFFFu - (unsigned)ci);
      atomicMax(&key[(size_t)bq * NA + row], k);
    }
  }
}

// ---------------------------------------------------------------------------
// K5 (fused): decode rescued keys + EXACT top-2048 via radix rank-select
// (threshold partition == sort partition for unique keys) + build merge lists
// + mask scan -> newidx + ownership output. One block per batch.
// ---------------------------------------------------------------------------
__global__ __launch_bounds__(1024) void k_select(
    const unsigned long long* __restrict__ rescueKey,
    const float* __restrict__ valA, const int* __restrict__ nodeA,
    int* __restrict__ sel, int* __restrict__ cnt, int* __restrict__ head,
    int* __restrict__ nxt, int* __restrict__ newidx,
    float* __restrict__ own) {
  __shared__ unsigned long long keys[NA];   // 32 KB
  __shared__ int nodeL[NA];                 // 16 KB
  __shared__ unsigned char selL[NA];        // 4 KB
  __shared__ int ni[NTOK];                  // 32 KB
  __shared__ unsigned tot[1024];            // 4 KB (scan scratch, reused)
  __shared__ unsigned hist[NA];             // 16 KB
  __shared__ unsigned long long cand[1024]; // 8 KB
  __shared__ unsigned shw[4];
  const int b = blockIdx.x, t = threadIdx.x;

  // 1) load + patch rescued rows
#pragma unroll
  for (int k4 = 0; k4 < 4; ++k4) {
    const int p = t + k4 * 1024;
    const size_t i = (size_t)b * NA + p;
    unsigned long long rk = rescueKey[i];
    float v; int nd;
    if (rk) {
      unsigned mono = (unsigned)(rk >> 32);
      unsigned u = (mono & 0x80000000u) ? (mono ^ 0x80000000u) : ~mono;
      v = __uint_as_float(u);
      nd = (int)(0xFFFFFFFFu - (unsigned)(rk & 0xFFFFFFFFull));
    } else {
      v = valA[i];
      nd = nodeA[i];
    }
    nodeL[p] = nd;
    unsigned u = __float_as_uint(v);
    unsigned mono = u ^ ((u >> 31) ? 0xFFFFFFFFu : 0x80000000u);
    keys[p] = ((unsigned long long)(~mono) << 32) | (unsigned)p;
  }
  __syncthreads();

  // 2) exact rank-(RSEL-1) threshold key; keys[] preserved
  const unsigned long long thr =
      rank_select_4096(keys, hist, cand, tot, shw, RSEL - 1, t);

  // 3) selection mask: key <= thr picks exactly RSEL keys (keys unique)
#pragma unroll
  for (int k4 = 0; k4 < 4; ++k4) {
    const int p = t + k4 * 1024;
    selL[p] = (keys[p] <= thr) ? 1 : 0;
  }
  __syncthreads();

  // 4) sel to global + build merge lists
#pragma unroll
  for (int k4 = 0; k4 < 4; ++k4) {
    const int p = t + k4 * 1024;
    const size_t i = (size_t)b * NA + p;
    int s = selL[p];
    sel[i] = s;
    if (s) {
      int dst = nodeL[p];
      atomicAdd(&cnt[(size_t)b * NA + dst], 1);
      nxt[i] = atomicExch(&head[(size_t)b * NA + dst], p);
    }
  }

  // 5) mask scan over 8192 positions -> newidx + ownership
  const int base = t * 8;
  int kept[8], run = 0;
#pragma unroll
  for (int e = 0; e < 8; ++e) {
    int idx = base + e;
    int kp = ((idx & 1) == 0) ? 1 : (selL[idx >> 1] ? 0 : 1);
    kept[e] = kp;
    run += kp;
  }
  tot[t] = (unsigned)run;
  __syncthreads();
  for (int off = 1; off < 1024; off <<= 1) {
    unsigned v = (t >= off) ? tot[t - off] : 0;
    __syncthreads();
    tot[t] += v;
    __syncthreads();
  }
  int cum = (int)tot[t] - run;
#pragma unroll
  for (int e = 0; e < 8; ++e) {
    cum += kept[e];
    ni[base + e] = cum - 1;
  }
  __syncthreads();
#pragma unroll
  for (int e = 0; e < 8; ++e) {
    int idx = base + e;
    int ow = kept[e] ? ni[idx] : ni[2 * nodeL[idx >> 1]];
    newidx[(size_t)b * NTOK + idx] = ni[idx];
    own[(size_t)b * NTOK + idx] = (float)ow;
  }
}

// ---------------------------------------------------------------------------
// K6: assemble x_final f32 (gather merges via linked list, divide, compact).
// 2 tokens per 256-thread block. (unchanged)
// ---------------------------------------------------------------------------
__global__ __launch_bounds__(256) void k_assemble(const float* __restrict__ X,
                                                  const int* __restrict__ sel,
                                                  const int* __restrict__ newidx,
                                                  const int* __restrict__ cnt,
                                                  const int* __restrict__ head,
                                                  const int* __restrict__ nxt,
                                                  float* __restrict__ out) {
  const int token = blockIdx.x * 2 + (threadIdx.x >> 7);
  const int bq = token >> 13, tp = token & (NTOK - 1);
  const int t = threadIdx.x & 127;
  if ((tp & 1) && sel[(size_t)bq * NA + (tp >> 1)]) return;
  float4 v = *(const float4*)(X + (size_t)token * CDIM + t * 4);
  if (!(tp & 1)) {
    size_t slot = (size_t)bq * NA + (tp >> 1);
    int c = cnt[slot];
    if (c > 0) {
      int kk = head[slot];
      while (kk >= 0) {
        float4 s = *(const float4*)(X + ((size_t)bq * NTOK + 2 * kk + 1) * CDIM + t * 4);
        v.x += s.x; v.y += s.y; v.z += s.z; v.w += s.w;
        kk = nxt[(size_t)bq * NA + kk];
      }
      float inv = 1.0f / (float)(1 + c);
      v.x *= inv; v.y *= inv; v.z *= inv; v.w *= inv;
    }
  }
  int dst = newidx[(size_t)bq * NTOK + tp];
  *(float4*)(out + ((size_t)bq * NKEEP + dst) * CDIM + t * 4) = v;
}

// ---------------------------------------------------------------------------
extern "C" void kernel_launch(void* const* d_in, const int* in_sizes, int n_in,
                              void* d_out, int out_size, void* d_ws, size_t ws_size,
                              hipStream_t stream) {
  const float* X    = (const float*)d_in[0];
  const float* W    = (const float*)d_in[1];
  const float* bias = (const float*)d_in[2];
  float* out = (float*)d_out;  // f32: x_final (4,6144,512) ++ ownership (4,8192)
  char* ws = (char*)d_ws;

  size_t o = 0;
  float* ma   = (float*)(ws + o); o += (size_t)BQ * NA * MDIM * 4;
  float* mb   = (float*)(ws + o); o += (size_t)BQ * NA * MDIM * 4;
  unsigned short* maH = (unsigned short*)(ws + o); o += (size_t)BQ * NA * MDIM * 2;
  unsigned short* maM = (unsigned short*)(ws + o); o += (size_t)BQ * NA * MDIM * 2;
  unsigned short* mbH = (unsigned short*)(ws + o); o += (size_t)BQ * NA * MDIM * 2;
  unsigned short* mbM = (unsigned short*)(ws + o); o += (size_t)BQ * NA * MDIM * 2;
  float* pv1  = (float*)(ws + o); o += (size_t)BQ * CSPL * NA * 4;
  int*   pi1  = (int*)(ws + o);   o += (size_t)BQ * CSPL * NA * 4;
  float* pv2  = (float*)(ws + o); o += (size_t)BQ * CSPL * NA * 4;
  float* valA = (float*)(ws + o); o += (size_t)BQ * NA * 4;
  int*   nodeA= (int*)(ws + o);   o += (size_t)BQ * NA * 4;
  int*   sel  = (int*)(ws + o);   o += (size_t)BQ * NA * 4;
  int*   cnt  = (int*)(ws + o);   o += (size_t)BQ * NA * 4;
  int*   head = (int*)(ws + o);   o += (size_t)BQ * NA * 4;
  int*   nxt  = (int*)(ws + o);   o += (size_t)BQ * NA * 4;
  int*   newidx = (int*)(ws + o); o += (size_t)BQ * NTOK * 4;
  int*   rescueCnt = (int*)(ws + o); o += 256;
  int*   rescueIdx = (int*)(ws + o); o += (size_t)BQ * RESCUE_CAP * 4;
  unsigned long long* rescueKey = (unsigned long long*)(ws + o); o += (size_t)BQ * NA * 8;
  (void)in_sizes; (void)n_in; (void)out_size; (void)ws_size;

  k_metric<<<512, 128, 0, stream>>>(X, W, bias, ma, mb, maH, maM, mbH, mbM);
  k_scores_mfma<<<BQ * 64 * CSPL, 256, 0, stream>>>(maH, maM, mbH, mbM, pv1, pi1, pv2);
  k_mergemark<<<BQ, 1024, 0, stream>>>(pv1, pi1, pv2, valA, nodeA,
                                       rescueCnt, rescueIdx, cnt, head, rescueKey);
  k_rescue<<<BQ * 256, 256, 0, stream>>>(ma, mb, rescueIdx, rescueCnt, rescueKey);
  k_select<<<BQ, 1024, 0, stream>>>(rescueKey, valA, nodeA, sel, cnt, head, nxt,
                                    newidx, out + (size_t)BQ * NKEEP * CDIM);
  k_assemble<<<BQ * NTOK / 2, 256, 0, stream>>>(X, sel, newidx, cnt, head, nxt, out);
}